// Round 3
// baseline (2724.304 us; speedup 1.0000x reference)
//
#include <hip/hip_runtime.h>

static constexpr int B_ = 16, T_ = 512, C_ = 512, L_ = 512, H_ = 8, HID_ = 2048;
static constexpr long NBT_ = (long)B_ * T_ * C_;   // 4,194,304 elements per [B,T,C] unit

// ---------------------------------------------------------------------------
// LayerNorm over last dim (=512). One wave per row, 8 elems/lane, shfl reduce.
// ---------------------------------------------------------------------------
__global__ __launch_bounds__(64)
void ln512(const float* __restrict__ in, const float* __restrict__ gam,
           const float* __restrict__ bet, float* __restrict__ out)
{
    const long r = blockIdx.x;
    const int lane = threadIdx.x;
    const float* rowp = in + r * 512 + lane * 8;
    float4 a = *(const float4*)rowp;
    float4 c = *(const float4*)(rowp + 4);
    float v[8] = {a.x, a.y, a.z, a.w, c.x, c.y, c.z, c.w};
    float s = 0.f;
#pragma unroll
    for (int i = 0; i < 8; i++) s += v[i];
#pragma unroll
    for (int m = 1; m < 64; m <<= 1) s += __shfl_xor(s, m);
    const float mean = s * (1.f / 512.f);
    float q = 0.f;
#pragma unroll
    for (int i = 0; i < 8; i++) { float d = v[i] - mean; q += d * d; }
#pragma unroll
    for (int m = 1; m < 64; m <<= 1) q += __shfl_xor(q, m);
    const float rstd = rsqrtf(q * (1.f / 512.f) + 1e-5f);
    float4 g0 = *(const float4*)(gam + lane * 8);
    float4 g1 = *(const float4*)(gam + lane * 8 + 4);
    float4 b0 = *(const float4*)(bet + lane * 8);
    float4 b1 = *(const float4*)(bet + lane * 8 + 4);
    float gg[8] = {g0.x, g0.y, g0.z, g0.w, g1.x, g1.y, g1.z, g1.w};
    float bb[8] = {b0.x, b0.y, b0.z, b0.w, b1.x, b1.y, b1.z, b1.w};
    float o[8];
#pragma unroll
    for (int i = 0; i < 8; i++) o[i] = (v[i] - mean) * rstd * gg[i] + bb[i];
    float* op = out + r * 512 + lane * 8;
    *(float4*)op       = make_float4(o[0], o[1], o[2], o[3]);
    *(float4*)(op + 4) = make_float4(o[4], o[5], o[6], o[7]);
}

// ---------------------------------------------------------------------------
// In-place softmax over rows of 512 with pre-scale 1/8 (=1/sqrt(64)).
// ---------------------------------------------------------------------------
__global__ __launch_bounds__(64)
void softmax512(float* __restrict__ buf)
{
    const long r = blockIdx.x;
    const int lane = threadIdx.x;
    float* rowp = buf + r * 512 + lane * 8;
    float4 a = *(const float4*)rowp;
    float4 c = *(const float4*)(rowp + 4);
    float v[8] = {a.x, a.y, a.z, a.w, c.x, c.y, c.z, c.w};
    float mx = -3.0e38f;
#pragma unroll
    for (int i = 0; i < 8; i++) { v[i] *= 0.125f; mx = fmaxf(mx, v[i]); }
#pragma unroll
    for (int m = 1; m < 64; m <<= 1) mx = fmaxf(mx, __shfl_xor(mx, m));
    float s = 0.f;
#pragma unroll
    for (int i = 0; i < 8; i++) { v[i] = __expf(v[i] - mx); s += v[i]; }
#pragma unroll
    for (int m = 1; m < 64; m <<= 1) s += __shfl_xor(s, m);
    const float inv = 1.f / s;
#pragma unroll
    for (int i = 0; i < 8; i++) v[i] *= inv;
    *(float4*)rowp       = make_float4(v[0], v[1], v[2], v[3]);
    *(float4*)(rowp + 4) = make_float4(v[4], v[5], v[6], v[7]);
}

// ---------------------------------------------------------------------------
// Spatial: softmax (scale 1/8) of nh head slices + accumulate mean (x 1/H=1/8)
// into out. sbuf slice h lives at sbuf + h*B*C*C; row r = b*C + n.
// ---------------------------------------------------------------------------
template<bool FIRST>
__global__ __launch_bounds__(64)
void softmax_accum512(const float* __restrict__ sbuf, float* __restrict__ out, int nh)
{
    const long r = blockIdx.x;
    const int lane = threadIdx.x;
    float acc[8] = {0.f,0.f,0.f,0.f,0.f,0.f,0.f,0.f};
    for (int hh = 0; hh < nh; ++hh) {
        const float* rowp = sbuf + (long)hh * B_ * C_ * C_ + r * 512 + lane * 8;
        float4 a = *(const float4*)rowp;
        float4 c = *(const float4*)(rowp + 4);
        float v[8] = {a.x, a.y, a.z, a.w, c.x, c.y, c.z, c.w};
        float mx = -3.0e38f;
#pragma unroll
        for (int i = 0; i < 8; i++) { v[i] *= 0.125f; mx = fmaxf(mx, v[i]); }
#pragma unroll
        for (int m = 1; m < 64; m <<= 1) mx = fmaxf(mx, __shfl_xor(mx, m));
        float s = 0.f;
#pragma unroll
        for (int i = 0; i < 8; i++) { v[i] = __expf(v[i] - mx); s += v[i]; }
#pragma unroll
        for (int m = 1; m < 64; m <<= 1) s += __shfl_xor(s, m);
        const float inv = 1.f / s;
#pragma unroll
        for (int i = 0; i < 8; i++) acc[i] += v[i] * inv;
    }
    float* op = out + r * 512 + lane * 8;
    if (FIRST) {
        *(float4*)op       = make_float4(acc[0]*0.125f, acc[1]*0.125f, acc[2]*0.125f, acc[3]*0.125f);
        *(float4*)(op + 4) = make_float4(acc[4]*0.125f, acc[5]*0.125f, acc[6]*0.125f, acc[7]*0.125f);
    } else {
        float4 e0 = *(const float4*)op;
        float4 e1 = *(const float4*)(op + 4);
        *(float4*)op       = make_float4(e0.x + acc[0]*0.125f, e0.y + acc[1]*0.125f,
                                         e0.z + acc[2]*0.125f, e0.w + acc[3]*0.125f);
        *(float4*)(op + 4) = make_float4(e1.x + acc[4]*0.125f, e1.y + acc[5]*0.125f,
                                         e1.z + acc[6]*0.125f, e1.w + acc[7]*0.125f);
    }
}

// ---------------------------------------------------------------------------
// Generic tiled fp32 GEMM.
//   TB=true : O = A @ Bm^T      (Bm is [N,K] row-major, row stride ldb)
//   TB=false: O = A @ Bm        (Bm is [K,N] row-major, row stride ldb)
// Optional epilogue: +bias[n], PReLU(alpha), +res.  Batched via blockIdx.z:
//   z1 = z / nz2, z2 = z % nz2; each pointer gets z1*s?1 + z2*s?2.
// Tiles: 128x128x16, 256 threads, 8x8 micro, reg-double-buffered staging.
// M must be a multiple of 128 (grid.x = M/128); N,K arbitrary mult. of 64/16.
// ---------------------------------------------------------------------------
template<bool TB, bool BIAS, bool PRELU, bool RES>
__global__ __launch_bounds__(256)
void gemm128(const float* __restrict__ A,  long sA1, long sA2, int lda,
             const float* __restrict__ Bm, long sB1, long sB2, int ldb,
             float*       __restrict__ O,  long sO1, long sO2, int ldo,
             const float* __restrict__ Rp, long sR1, long sR2, int ldr,
             const float* __restrict__ bias, const float* __restrict__ alphap,
             int N, int K, int nz2)
{
    __shared__ __align__(16) float As[16][132];
    __shared__ __align__(16) float Bs[16][132];

    const int t  = threadIdx.x;
    const int z  = blockIdx.z;
    const int z1 = z / nz2, z2 = z - z1 * nz2;
    const long bm = (long)blockIdx.x * 128;
    const int  bn = blockIdx.y * 128;

    const float* Ab = A  + sA1 * z1 + sA2 * z2 + bm * lda;
    const float* Bb = Bm + sB1 * z1 + sB2 * z2;

    // loader thread mapping
    const int am  = t >> 2;          // 0..63  (row within tile, +64 for 2nd)
    const int ak  = (t & 3) << 2;    // 0,4,8,12
    const int bk  = t >> 4;          // 0..15  (!TB row)
    const int bnn = (t & 15) << 3;   // 0..120 (!TB col)

    const float* Ap = Ab + (long)am * lda + ak;
    const float* Bp;
    bool bval0, bval1;
    if (TB) {
        Bp = Bb + (long)(bn + am) * ldb + ak;
        bval0 = (bn + am)      < N;
        bval1 = (bn + am + 64) < N;
    } else {
        Bp = Bb + (long)bk * ldb + bn + bnn;
        bval0 = (bn + bnn)     < N;
        bval1 = (bn + bnn + 4) < N;
    }

    float4 ra0, ra1, rb0, rb1;
    const float4 f4z = make_float4(0.f, 0.f, 0.f, 0.f);

    auto loadT = [&](int k0) {
        ra0 = *(const float4*)(Ap + k0);
        ra1 = *(const float4*)(Ap + (long)64 * lda + k0);
        if (TB) {
            rb0 = bval0 ? *(const float4*)(Bp + k0) : f4z;
            rb1 = bval1 ? *(const float4*)(Bp + (long)64 * ldb + k0) : f4z;
        } else {
            rb0 = bval0 ? *(const float4*)(Bp + (long)k0 * ldb) : f4z;
            rb1 = bval1 ? *(const float4*)(Bp + (long)k0 * ldb + 4) : f4z;
        }
    };
    auto stash = [&]() {
        const float* pa0 = (const float*)&ra0;
        const float* pa1 = (const float*)&ra1;
#pragma unroll
        for (int i = 0; i < 4; i++) { As[ak + i][am] = pa0[i]; As[ak + i][am + 64] = pa1[i]; }
        if (TB) {
            const float* pb0 = (const float*)&rb0;
            const float* pb1 = (const float*)&rb1;
#pragma unroll
            for (int i = 0; i < 4; i++) { Bs[ak + i][am] = pb0[i]; Bs[ak + i][am + 64] = pb1[i]; }
        } else {
            *(float4*)&Bs[bk][bnn]     = rb0;
            *(float4*)&Bs[bk][bnn + 4] = rb1;
        }
    };

    const int wave = t >> 6, lane = t & 63;
    const int mr = ((wave >> 1) << 6) + ((lane >> 3) << 3);
    const int nr = ((wave & 1) << 6) + ((lane & 7) << 3);

    float acc[8][8];
#pragma unroll
    for (int i = 0; i < 8; i++)
#pragma unroll
        for (int j = 0; j < 8; j++) acc[i][j] = 0.f;

    const int KT = K >> 4;
    loadT(0);
    stash();
    __syncthreads();
    for (int kt = 0; kt < KT; ++kt) {
        if (kt + 1 < KT) loadT((kt + 1) << 4);
#pragma unroll
        for (int k = 0; k < 16; k++) {
            float4 a0 = *(const float4*)&As[k][mr];
            float4 a1 = *(const float4*)&As[k][mr + 4];
            float4 b0 = *(const float4*)&Bs[k][nr];
            float4 b1 = *(const float4*)&Bs[k][nr + 4];
            const float av[8] = {a0.x, a0.y, a0.z, a0.w, a1.x, a1.y, a1.z, a1.w};
            const float bv[8] = {b0.x, b0.y, b0.z, b0.w, b1.x, b1.y, b1.z, b1.w};
#pragma unroll
            for (int i = 0; i < 8; i++)
#pragma unroll
                for (int j = 0; j < 8; j++) acc[i][j] = fmaf(av[i], bv[j], acc[i][j]);
        }
        if (kt + 1 < KT) {
            __syncthreads();
            stash();
            __syncthreads();
        }
    }

    // epilogue
    const int ncol = bn + nr;
    if (ncol >= N) return;

    float bvv[8] = {0.f,0.f,0.f,0.f,0.f,0.f,0.f,0.f};
    if (BIAS) {
        float4 q0 = *(const float4*)(bias + ncol);
        float4 q1 = *(const float4*)(bias + ncol + 4);
        bvv[0]=q0.x; bvv[1]=q0.y; bvv[2]=q0.z; bvv[3]=q0.w;
        bvv[4]=q1.x; bvv[5]=q1.y; bvv[6]=q1.z; bvv[7]=q1.w;
    }
    const float alpha = PRELU ? alphap[0] : 0.f;
    float* Ob = O + sO1 * z1 + sO2 * z2 + bm * ldo;
    const float* Rb = nullptr;
    if (RES) Rb = Rp + sR1 * z1 + sR2 * z2 + bm * ldr;

#pragma unroll
    for (int i = 0; i < 8; i++) {
        const int row = mr + i;
        float o[8];
#pragma unroll
        for (int j = 0; j < 8; j++) {
            float x = acc[i][j];
            if (BIAS) x += bvv[j];
            if (PRELU) x = (x >= 0.f) ? x : alpha * x;
            o[j] = x;
        }
        if (RES) {
            const float* rp = Rb + (long)row * ldr + ncol;
            float4 r0 = *(const float4*)rp;
            float4 r1 = *(const float4*)(rp + 4);
            o[0] += r0.x; o[1] += r0.y; o[2] += r0.z; o[3] += r0.w;
            o[4] += r1.x; o[5] += r1.y; o[6] += r1.z; o[7] += r1.w;
        }
        float* op = Ob + (long)row * ldo + ncol;
        *(float4*)op       = make_float4(o[0], o[1], o[2], o[3]);
        *(float4*)(op + 4) = make_float4(o[4], o[5], o[6], o[7]);
    }
}

// ---------------------------------------------------------------------------
extern "C" void kernel_launch(void* const* d_in, const int* in_sizes, int n_in,
                              void* d_out, int out_size, void* d_ws, size_t ws_size,
                              hipStream_t stream)
{
    (void)in_sizes; (void)n_in; (void)out_size;
    const float* src    = (const float*)d_in[0];
    const float* ssrc   = (const float*)d_in[1];
    const float* Wq_t   = (const float*)d_in[2];
    const float* Wk_t   = (const float*)d_in[3];
    const float* Wv_t   = (const float*)d_in[4];
    const float* Wo_t   = (const float*)d_in[5];
    const float* Wq_s   = (const float*)d_in[6];
    const float* Wk_s   = (const float*)d_in[7];
    const float* W1     = (const float*)d_in[8];
    const float* b1     = (const float*)d_in[9];
    const float* W2     = (const float*)d_in[10];
    const float* b2     = (const float*)d_in[11];
    const float* tsW1   = (const float*)d_in[12];
    const float* tsb1   = (const float*)d_in[13];
    const float* tsW2   = (const float*)d_in[14];
    const float* tsb2   = (const float*)d_in[15];
    const float* alphap = (const float*)d_in[16];
    const float* g1     = (const float*)d_in[17];
    const float* be1    = (const float*)d_in[18];
    const float* g2     = (const float*)d_in[19];
    const float* be2    = (const float*)d_in[20];
    const float* tsg1   = (const float*)d_in[21];
    const float* tsbe1  = (const float*)d_in[22];
    const float* tsg2   = (const float*)d_in[23];
    const float* tsbe2  = (const float*)d_in[24];
    const float* sg     = (const float*)d_in[25];
    const float* sbe    = (const float*)d_in[26];

    float* ws   = (float*)d_ws;
    float* xbuf = ws;                 // LN outputs (reused)
    float* qb   = ws + 1 * NBT_;      // q   | sp
    float* kb   = ws + 2 * NBT_;      // k   | qs
    float* vb   = ws + 3 * NBT_;      // v   | ks
    float* attn = ws + 4 * NBT_;      // attn| mix_out
    float* src2 = ws + 5 * NBT_;      // post temporal residual
    float* hbuf = ws + 6 * NBT_;      // FFN hidden chunk
    float* src3 = ws + 7 * NBT_;      // post FFN1 residual
    float* out_ts = (float*)d_out;            // ts_out  [B,T,C]
    float* out_sw = (float*)d_out + NBT_;     // spatial_weights [B,C,C]

    // adaptive head-group size for score buffer
    const size_t unit_b = (size_t)NBT_ * 4;
    const size_t ua = ws_size / unit_b;
    int G; float* sbuf;
    if      (ua >= 16) { G = 8; sbuf = ws + 8 * NBT_; }
    else if (ua >= 12) { G = 4; sbuf = ws + 8 * NBT_; }
    else if (ua >= 10) { G = 2; sbuf = ws + 8 * NBT_; }
    else if (ua >=  9) { G = 1; sbuf = ws + 8 * NBT_; }
    else               { G = 1; sbuf = hbuf; }   // alias: never concurrently live

    const long sTT  = (long)T_ * T_;
    const long sTC  = (long)T_ * C_;
    const long sBTT = (long)B_ * sTT;
    const long sBCC = (long)B_ * C_ * C_;

    // ---- temporal attention block ----
    ln512<<<dim3(B_ * T_), 64, 0, stream>>>(src, g1, be1, xbuf);
    gemm128<true,false,false,false><<<dim3(64,4,1),256,0,stream>>>(
        xbuf,0,0,C_,  Wq_t,0,0,C_,  qb,0,0,C_,  nullptr,0,0,0, nullptr,nullptr, C_, C_, 1);
    gemm128<true,false,false,false><<<dim3(64,4,1),256,0,stream>>>(
        xbuf,0,0,C_,  Wk_t,0,0,C_,  kb,0,0,C_,  nullptr,0,0,0, nullptr,nullptr, C_, C_, 1);
    gemm128<true,false,false,false><<<dim3(64,4,1),256,0,stream>>>(
        xbuf,0,0,C_,  Wv_t,0,0,C_,  vb,0,0,C_,  nullptr,0,0,0, nullptr,nullptr, C_, C_, 1);

    for (int g0 = 0; g0 < H_; g0 += G) {
        gemm128<true,false,false,false><<<dim3(4,4,G*B_),256,0,stream>>>(
            qb + g0*64, 64, sTC, C_,
            kb + g0*64, 64, sTC, C_,
            sbuf, sBTT, sTT, T_,
            nullptr,0,0,0, nullptr,nullptr, T_, 64, B_);
        softmax512<<<dim3(G * B_ * T_), 64, 0, stream>>>(sbuf);
        gemm128<false,false,false,false><<<dim3(4,1,G*B_),256,0,stream>>>(
            sbuf, sBTT, sTT, T_,
            vb + g0*64, 64, sTC, C_,
            attn + g0*64, 64, sTC, C_,
            nullptr,0,0,0, nullptr,nullptr, 64, T_, B_);
    }
    gemm128<true,false,false,true><<<dim3(64,4,1),256,0,stream>>>(
        attn,0,0,C_,  Wo_t,0,0,C_,  src2,0,0,C_,  src,0,0,C_, nullptr,nullptr, C_, C_, 1);

    // ---- FFN block 1 (4 chunks of 512 hidden) ----
    ln512<<<dim3(B_ * T_), 64, 0, stream>>>(src2, g2, be2, xbuf);
    for (int j = 0; j < 4; j++) {
        gemm128<true,true,true,false><<<dim3(64,4,1),256,0,stream>>>(
            xbuf,0,0,C_,  W1 + (long)j*512*C_,0,0,C_,  hbuf,0,0,512,
            nullptr,0,0,0,  b1 + j*512, alphap, 512, C_, 1);
        if (j == 0)
            gemm128<true,true,false,true><<<dim3(64,4,1),256,0,stream>>>(
                hbuf,0,0,512,  W2 + j*512,0,0,HID_,  src3,0,0,C_,  src2,0,0,C_,
                b2, nullptr, C_, 512, 1);
        else
            gemm128<true,false,false,true><<<dim3(64,4,1),256,0,stream>>>(
                hbuf,0,0,512,  W2 + j*512,0,0,HID_,  src3,0,0,C_,  src3,0,0,C_,
                nullptr, nullptr, C_, 512, 1);
    }

    // ---- spatial attention (weights only, mean over heads) ----
    ln512<<<dim3(B_ * C_), 64, 0, stream>>>(ssrc, sg, sbe, qb);
    gemm128<true,false,false,false><<<dim3(64,4,1),256,0,stream>>>(
        qb,0,0,L_,  Wq_s,0,0,L_,  kb,0,0,512,  nullptr,0,0,0, nullptr,nullptr, 512, L_, 1);
    gemm128<true,false,false,false><<<dim3(64,4,1),256,0,stream>>>(
        qb,0,0,L_,  Wk_s,0,0,L_,  vb,0,0,512,  nullptr,0,0,0, nullptr,nullptr, 512, L_, 1);
    for (int g0 = 0; g0 < H_; g0 += G) {
        gemm128<true,false,false,false><<<dim3(4,4,G*B_),256,0,stream>>>(
            kb + g0*64, 64, (long)C_*512, 512,
            vb + g0*64, 64, (long)C_*512, 512,
            sbuf, sBCC, (long)C_*C_, C_,
            nullptr,0,0,0, nullptr,nullptr, C_, 64, B_);
        if (g0 == 0) softmax_accum512<true ><<<dim3(B_ * C_), 64, 0, stream>>>(sbuf, out_sw, G);
        else         softmax_accum512<false><<<dim3(B_ * C_), 64, 0, stream>>>(sbuf, out_sw, G);
    }

    // ---- temporal-spatial mixing ----
    ln512<<<dim3(B_ * T_), 64, 0, stream>>>(src3, tsg1, tsbe1, xbuf);
    gemm128<true,false,false,true><<<dim3(4,4,16),256,0,stream>>>(
        xbuf,   0, sTC, C_,
        out_sw, 0, (long)C_*C_, C_,
        attn,   0, sTC, C_,
        src3,   0, sTC, C_,
        nullptr, nullptr, C_, C_, 16);

    // ---- FFN block 2 (final output into d_out) ----
    ln512<<<dim3(B_ * T_), 64, 0, stream>>>(attn, tsg2, tsbe2, xbuf);
    for (int j = 0; j < 4; j++) {
        gemm128<true,true,true,false><<<dim3(64,4,1),256,0,stream>>>(
            xbuf,0,0,C_,  tsW1 + (long)j*512*C_,0,0,C_,  hbuf,0,0,512,
            nullptr,0,0,0,  tsb1 + j*512, alphap, 512, C_, 1);
        if (j == 0)
            gemm128<true,true,false,true><<<dim3(64,4,1),256,0,stream>>>(
                hbuf,0,0,512,  tsW2 + j*512,0,0,HID_,  out_ts,0,0,C_,  attn,0,0,C_,
                tsb2, nullptr, C_, 512, 1);
        else
            gemm128<true,false,false,true><<<dim3(64,4,1),256,0,stream>>>(
                hbuf,0,0,512,  tsW2 + j*512,0,0,HID_,  out_ts,0,0,C_,  out_ts,0,0,C_,
                nullptr, nullptr, C_, 512, 1);
    }
}

// Round 6
// 976.030 us; speedup vs baseline: 2.7912x; 2.7912x over previous
//
#include <hip/hip_runtime.h>

static constexpr int B_ = 16, T_ = 512, C_ = 512, L_ = 512, H_ = 8, HID_ = 2048;
static constexpr long NBT_ = (long)B_ * T_ * C_;   // 4,194,304 elements per [B,T,C] unit

typedef _Float16 half8_t __attribute__((ext_vector_type(8)));
typedef float    f32x4   __attribute__((ext_vector_type(4)));

// split fp32 -> f16 hi + f16 lo (hi+lo carries ~22 mantissa bits)
#define SPL(H, L, idx, val) { float _x = (val); _Float16 _h = (_Float16)_x; \
                              (H)[idx] = _h; (L)[idx] = (_Float16)(_x - (float)_h); }

// ---------------------------------------------------------------------------
// LayerNorm over last dim (=512). One wave per row, 8 elems/lane, shfl reduce.
// ---------------------------------------------------------------------------
__global__ __launch_bounds__(64)
void ln512(const float* __restrict__ in, const float* __restrict__ gam,
           const float* __restrict__ bet, float* __restrict__ out)
{
    const long r = blockIdx.x;
    const int lane = threadIdx.x;
    const float* rowp = in + r * 512 + lane * 8;
    float4 a = *(const float4*)rowp;
    float4 c = *(const float4*)(rowp + 4);
    float v[8] = {a.x, a.y, a.z, a.w, c.x, c.y, c.z, c.w};
    float s = 0.f;
#pragma unroll
    for (int i = 0; i < 8; i++) s += v[i];
#pragma unroll
    for (int m = 1; m < 64; m <<= 1) s += __shfl_xor(s, m);
    const float mean = s * (1.f / 512.f);
    float q = 0.f;
#pragma unroll
    for (int i = 0; i < 8; i++) { float d = v[i] - mean; q += d * d; }
#pragma unroll
    for (int m = 1; m < 64; m <<= 1) q += __shfl_xor(q, m);
    const float rstd = rsqrtf(q * (1.f / 512.f) + 1e-5f);
    float4 g0 = *(const float4*)(gam + lane * 8);
    float4 g1 = *(const float4*)(gam + lane * 8 + 4);
    float4 b0 = *(const float4*)(bet + lane * 8);
    float4 b1 = *(const float4*)(bet + lane * 8 + 4);
    float gg[8] = {g0.x, g0.y, g0.z, g0.w, g1.x, g1.y, g1.z, g1.w};
    float bb[8] = {b0.x, b0.y, b0.z, b0.w, b1.x, b1.y, b1.z, b1.w};
    float o[8];
#pragma unroll
    for (int i = 0; i < 8; i++) o[i] = (v[i] - mean) * rstd * gg[i] + bb[i];
    float* op = out + r * 512 + lane * 8;
    *(float4*)op       = make_float4(o[0], o[1], o[2], o[3]);
    *(float4*)(op + 4) = make_float4(o[4], o[5], o[6], o[7]);
}

// ---------------------------------------------------------------------------
// In-place softmax over rows of 512 with pre-scale 1/8 (=1/sqrt(64)).
// ---------------------------------------------------------------------------
__global__ __launch_bounds__(64)
void softmax512(float* __restrict__ buf)
{
    const long r = blockIdx.x;
    const int lane = threadIdx.x;
    float* rowp = buf + r * 512 + lane * 8;
    float4 a = *(const float4*)rowp;
    float4 c = *(const float4*)(rowp + 4);
    float v[8] = {a.x, a.y, a.z, a.w, c.x, c.y, c.z, c.w};
    float mx = -3.0e38f;
#pragma unroll
    for (int i = 0; i < 8; i++) { v[i] *= 0.125f; mx = fmaxf(mx, v[i]); }
#pragma unroll
    for (int m = 1; m < 64; m <<= 1) mx = fmaxf(mx, __shfl_xor(mx, m));
    float s = 0.f;
#pragma unroll
    for (int i = 0; i < 8; i++) { v[i] = __expf(v[i] - mx); s += v[i]; }
#pragma unroll
    for (int m = 1; m < 64; m <<= 1) s += __shfl_xor(s, m);
    const float inv = 1.f / s;
#pragma unroll
    for (int i = 0; i < 8; i++) v[i] *= inv;
    *(float4*)rowp       = make_float4(v[0], v[1], v[2], v[3]);
    *(float4*)(rowp + 4) = make_float4(v[4], v[5], v[6], v[7]);
}

// ---------------------------------------------------------------------------
// Spatial: softmax (scale 1/8) of nh head slices + accumulate mean (x 1/H=1/8)
// into out. sbuf slice h lives at sbuf + h*B*C*C; row r = b*C + n.
// ---------------------------------------------------------------------------
template<bool FIRST>
__global__ __launch_bounds__(64)
void softmax_accum512(const float* __restrict__ sbuf, float* __restrict__ out, int nh)
{
    const long r = blockIdx.x;
    const int lane = threadIdx.x;
    float acc[8] = {0.f,0.f,0.f,0.f,0.f,0.f,0.f,0.f};
    for (int hh = 0; hh < nh; ++hh) {
        const float* rowp = sbuf + (long)hh * B_ * C_ * C_ + r * 512 + lane * 8;
        float4 a = *(const float4*)rowp;
        float4 c = *(const float4*)(rowp + 4);
        float v[8] = {a.x, a.y, a.z, a.w, c.x, c.y, c.z, c.w};
        float mx = -3.0e38f;
#pragma unroll
        for (int i = 0; i < 8; i++) { v[i] *= 0.125f; mx = fmaxf(mx, v[i]); }
#pragma unroll
        for (int m = 1; m < 64; m <<= 1) mx = fmaxf(mx, __shfl_xor(mx, m));
        float s = 0.f;
#pragma unroll
        for (int i = 0; i < 8; i++) { v[i] = __expf(v[i] - mx); s += v[i]; }
#pragma unroll
        for (int m = 1; m < 64; m <<= 1) s += __shfl_xor(s, m);
        const float inv = 1.f / s;
#pragma unroll
        for (int i = 0; i < 8; i++) acc[i] += v[i] * inv;
    }
    float* op = out + r * 512 + lane * 8;
    if (FIRST) {
        *(float4*)op       = make_float4(acc[0]*0.125f, acc[1]*0.125f, acc[2]*0.125f, acc[3]*0.125f);
        *(float4*)(op + 4) = make_float4(acc[4]*0.125f, acc[5]*0.125f, acc[6]*0.125f, acc[7]*0.125f);
    } else {
        float4 e0 = *(const float4*)op;
        float4 e1 = *(const float4*)(op + 4);
        *(float4*)op       = make_float4(e0.x + acc[0]*0.125f, e0.y + acc[1]*0.125f,
                                         e0.z + acc[2]*0.125f, e0.w + acc[3]*0.125f);
        *(float4*)(op + 4) = make_float4(e1.x + acc[4]*0.125f, e1.y + acc[5]*0.125f,
                                         e1.z + acc[6]*0.125f, e1.w + acc[7]*0.125f);
    }
}

// ---------------------------------------------------------------------------
// Split-f16 MFMA GEMM: fp32 in/out, fp32-accuracy via hi/lo f16 decomposition.
//   TB=true : O = A @ Bm^T  (Bm [N,K] row-major)  — all N=512 call sites
//   TB=false: O = A @ Bm    (Bm [K,N] row-major)  — PV only (N=64)
// Epilogue: +bias[n], PReLU(alpha), +res.  Batched via blockIdx.z (z1*nz2+z2).
// Tile: BM=128 x BN=64 x BK=32; 256 threads = 4 waves (2x2); wave tile 64x32;
// per k-step/wave: 8 frags x 3 mfma_f32_16x16x32_f16 = 24 MFMA.
// A/B operand k-mapping cancels (same (lane,j)->k both sides); C/D mapping is
// the HW-verified col=lane&15, row=(lane>>4)*4+reg.
// ---------------------------------------------------------------------------
template<bool TB, bool BIAS, bool PRELU, bool RES>
__global__ __launch_bounds__(256)
void gemm_mfma(const float* __restrict__ A,  long sA1, long sA2, int lda,
               const float* __restrict__ Bm, long sB1, long sB2, int ldb,
               float*       __restrict__ O,  long sO1, long sO2, int ldo,
               const float* __restrict__ Rp, long sR1, long sR2, int ldr,
               const float* __restrict__ bias, const float* __restrict__ alphap,
               int N, int K, int nz2)
{
    // K-major LDS tiles, row stride 40 halves (80 B -> ~2-way conflicts, free)
    __shared__ __align__(16) _Float16 AsH[128 * 40];
    __shared__ __align__(16) _Float16 AsL[128 * 40];
    __shared__ __align__(16) _Float16 BsH[64 * 40];
    __shared__ __align__(16) _Float16 BsL[64 * 40];

    const int t  = threadIdx.x;
    const int z  = blockIdx.z;
    const int z1 = z / nz2, z2 = z - z1 * nz2;
    const long bm = (long)blockIdx.x * 128;
    const int  bn = blockIdx.y * 64;

    const float* Ab = A  + sA1 * z1 + sA2 * z2 + bm * lda;
    const float* Bb = Bm + sB1 * z1 + sB2 * z2;

    // A staging: 128 rows x 32 k / 256 thr = 16 elems (4 float4)
    const int ar = t >> 1;              // 0..127
    const int ak = (t & 1) << 4;        // 0,16
    const float* Ap = Ab + (long)ar * lda + ak;
    // B staging TB=true: 64 rows x 32 k / 256 thr = 8 elems (2 float4)
    const int br = t >> 2;              // 0..63
    const int bk = (t & 3) << 3;        // 0,8,16,24
    const float* BpT = Bb + (long)(bn + br) * ldb + bk;
    // B staging TB=false (transpose): 32 k-rows x 64 n / 256 thr
    const int fk = t >> 3;              // 0..31
    const int fn = (t & 7) << 2;        // 0,4,..,28
    const float* BpF = Bb + (long)fk * ldb + bn + fn;

    const int wave = t >> 6, lane = t & 63;
    const int wm = (wave >> 1) << 6;    // 0,64
    const int wn = (wave & 1) << 5;    // 0,32
    const int fr = lane & 15;
    const int k8 = (lane >> 4) << 3;    // 0,8,16,24

    f32x4 acc[4][2];
#pragma unroll
    for (int i = 0; i < 4; i++)
#pragma unroll
        for (int j = 0; j < 2; j++) acc[i][j] = (f32x4)0.f;

    const int KT = K >> 5;
    for (int kt = 0; kt < KT; ++kt) {
        if (kt) __syncthreads();
        // ---- stage A (hi/lo split)
        {
            const float* p = Ap + (kt << 5);
            float4 v0 = *(const float4*)(p);
            float4 v1 = *(const float4*)(p + 4);
            float4 v2 = *(const float4*)(p + 8);
            float4 v3 = *(const float4*)(p + 12);
            half8_t h0, l0, h1, l1;
            SPL(h0, l0, 0, v0.x) SPL(h0, l0, 1, v0.y) SPL(h0, l0, 2, v0.z) SPL(h0, l0, 3, v0.w)
            SPL(h0, l0, 4, v1.x) SPL(h0, l0, 5, v1.y) SPL(h0, l0, 6, v1.z) SPL(h0, l0, 7, v1.w)
            SPL(h1, l1, 0, v2.x) SPL(h1, l1, 1, v2.y) SPL(h1, l1, 2, v2.z) SPL(h1, l1, 3, v2.w)
            SPL(h1, l1, 4, v3.x) SPL(h1, l1, 5, v3.y) SPL(h1, l1, 6, v3.z) SPL(h1, l1, 7, v3.w)
            const int o = ar * 40 + ak;
            *(half8_t*)&AsH[o]     = h0;  *(half8_t*)&AsH[o + 8] = h1;
            *(half8_t*)&AsL[o]     = l0;  *(half8_t*)&AsL[o + 8] = l1;
        }
        // ---- stage B
        if (TB) {
            const float* p = BpT + (kt << 5);
            float4 v0 = *(const float4*)(p);
            float4 v1 = *(const float4*)(p + 4);
            half8_t h, l;
            SPL(h, l, 0, v0.x) SPL(h, l, 1, v0.y) SPL(h, l, 2, v0.z) SPL(h, l, 3, v0.w)
            SPL(h, l, 4, v1.x) SPL(h, l, 5, v1.y) SPL(h, l, 6, v1.z) SPL(h, l, 7, v1.w)
            const int o = br * 40 + bk;
            *(half8_t*)&BsH[o] = h;
            *(half8_t*)&BsL[o] = l;
        } else {
            const float* p = BpF + ((long)(kt << 5)) * ldb;
#pragma unroll
            for (int g = 0; g < 2; ++g) {
                const int n = fn + (g << 5);
                float4 v = *(const float4*)(p + (g << 5));
                float e[4] = {v.x, v.y, v.z, v.w};
#pragma unroll
                for (int c = 0; c < 4; ++c) {
                    const float x = (bn + n + c < N) ? e[c] : 0.f;
                    _Float16 hh = (_Float16)x;
                    BsH[(n + c) * 40 + fk] = hh;
                    BsL[(n + c) * 40 + fk] = (_Float16)(x - (float)hh);
                }
            }
        }
        __syncthreads();
        // ---- fragments + 3-term MFMA
        half8_t aH[4], aL[4], bH[2], bL[2];
#pragma unroll
        for (int i = 0; i < 4; ++i) {
            const int o = (wm + i * 16 + fr) * 40 + k8;
            aH[i] = *(const half8_t*)&AsH[o];
            aL[i] = *(const half8_t*)&AsL[o];
        }
#pragma unroll
        for (int j = 0; j < 2; ++j) {
            const int o = (wn + j * 16 + fr) * 40 + k8;
            bH[j] = *(const half8_t*)&BsH[o];
            bL[j] = *(const half8_t*)&BsL[o];
        }
#pragma unroll
        for (int i = 0; i < 4; ++i)
#pragma unroll
            for (int j = 0; j < 2; ++j) {
                acc[i][j] = __builtin_amdgcn_mfma_f32_16x16x32_f16(aH[i], bH[j], acc[i][j], 0, 0, 0);
                acc[i][j] = __builtin_amdgcn_mfma_f32_16x16x32_f16(aH[i], bL[j], acc[i][j], 0, 0, 0);
                acc[i][j] = __builtin_amdgcn_mfma_f32_16x16x32_f16(aL[i], bH[j], acc[i][j], 0, 0, 0);
            }
    }

    // ---- epilogue
    const float alpha = PRELU ? alphap[0] : 0.f;
    float* Ob = O + sO1 * z1 + sO2 * z2 + bm * ldo;
    const float* Rb = nullptr;
    if (RES) Rb = Rp + sR1 * z1 + sR2 * z2 + bm * ldr;
    const int r4 = (lane >> 4) << 2;    // 0,4,8,12
#pragma unroll
    for (int i = 0; i < 4; ++i) {
#pragma unroll
        for (int j = 0; j < 2; ++j) {
            const int col = bn + wn + j * 16 + fr;
            if (col >= N) continue;
            const float bv = BIAS ? bias[col] : 0.f;
#pragma unroll
            for (int r = 0; r < 4; ++r) {
                const int row = wm + i * 16 + r4 + r;
                float x = acc[i][j][r];
                if (BIAS) x += bv;
                if (PRELU) x = (x >= 0.f) ? x : alpha * x;
                if (RES) x += Rb[(long)row * ldr + col];
                Ob[(long)row * ldo + col] = x;
            }
        }
    }
}

// ---------------------------------------------------------------------------
extern "C" void kernel_launch(void* const* d_in, const int* in_sizes, int n_in,
                              void* d_out, int out_size, void* d_ws, size_t ws_size,
                              hipStream_t stream)
{
    (void)in_sizes; (void)n_in; (void)out_size;
    const float* src    = (const float*)d_in[0];
    const float* ssrc   = (const float*)d_in[1];
    const float* Wq_t   = (const float*)d_in[2];
    const float* Wk_t   = (const float*)d_in[3];
    const float* Wv_t   = (const float*)d_in[4];
    const float* Wo_t   = (const float*)d_in[5];
    const float* Wq_s   = (const float*)d_in[6];
    const float* Wk_s   = (const float*)d_in[7];
    const float* W1     = (const float*)d_in[8];
    const float* b1     = (const float*)d_in[9];
    const float* W2     = (const float*)d_in[10];
    const float* b2     = (const float*)d_in[11];
    const float* tsW1   = (const float*)d_in[12];
    const float* tsb1   = (const float*)d_in[13];
    const float* tsW2   = (const float*)d_in[14];
    const float* tsb2   = (const float*)d_in[15];
    const float* alphap = (const float*)d_in[16];
    const float* g1     = (const float*)d_in[17];
    const float* be1    = (const float*)d_in[18];
    const float* g2     = (const float*)d_in[19];
    const float* be2    = (const float*)d_in[20];
    const float* tsg1   = (const float*)d_in[21];
    const float* tsbe1  = (const float*)d_in[22];
    const float* tsg2   = (const float*)d_in[23];
    const float* tsbe2  = (const float*)d_in[24];
    const float* sg     = (const float*)d_in[25];
    const float* sbe    = (const float*)d_in[26];

    float* ws   = (float*)d_ws;
    float* xbuf = ws;                 // LN outputs (reused)
    float* qb   = ws + 1 * NBT_;      // q   | sp
    float* kb   = ws + 2 * NBT_;      // k   | qs
    float* vb   = ws + 3 * NBT_;      // v   | ks
    float* attn = ws + 4 * NBT_;      // attn| mix_out
    float* src2 = ws + 5 * NBT_;      // post temporal residual
    float* hbuf = ws + 6 * NBT_;      // FFN hidden chunk
    float* src3 = ws + 7 * NBT_;      // post FFN1 residual
    float* out_ts = (float*)d_out;            // ts_out  [B,T,C]
    float* out_sw = (float*)d_out + NBT_;     // spatial_weights [B,C,C]

    // adaptive head-group size for score buffer
    const size_t unit_b = (size_t)NBT_ * 4;
    const size_t ua = ws_size / unit_b;
    int G; float* sbuf;
    if      (ua >= 16) { G = 8; sbuf = ws + 8 * NBT_; }
    else if (ua >= 12) { G = 4; sbuf = ws + 8 * NBT_; }
    else if (ua >= 10) { G = 2; sbuf = ws + 8 * NBT_; }
    else if (ua >=  9) { G = 1; sbuf = ws + 8 * NBT_; }
    else               { G = 1; sbuf = hbuf; }   // alias: never concurrently live

    const long sTT  = (long)T_ * T_;
    const long sTC  = (long)T_ * C_;
    const long sBTT = (long)B_ * sTT;
    const long sBCC = (long)B_ * C_ * C_;

    // ---- temporal attention block ----
    ln512<<<dim3(B_ * T_), 64, 0, stream>>>(src, g1, be1, xbuf);
    gemm_mfma<true,false,false,false><<<dim3(64,8,1),256,0,stream>>>(
        xbuf,0,0,C_,  Wq_t,0,0,C_,  qb,0,0,C_,  nullptr,0,0,0, nullptr,nullptr, C_, C_, 1);
    gemm_mfma<true,false,false,false><<<dim3(64,8,1),256,0,stream>>>(
        xbuf,0,0,C_,  Wk_t,0,0,C_,  kb,0,0,C_,  nullptr,0,0,0, nullptr,nullptr, C_, C_, 1);
    gemm_mfma<true,false,false,false><<<dim3(64,8,1),256,0,stream>>>(
        xbuf,0,0,C_,  Wv_t,0,0,C_,  vb,0,0,C_,  nullptr,0,0,0, nullptr,nullptr, C_, C_, 1);

    for (int g0 = 0; g0 < H_; g0 += G) {
        gemm_mfma<true,false,false,false><<<dim3(4,8,G*B_),256,0,stream>>>(
            qb + g0*64, 64, sTC, C_,
            kb + g0*64, 64, sTC, C_,
            sbuf, sBTT, sTT, T_,
            nullptr,0,0,0, nullptr,nullptr, T_, 64, B_);
        softmax512<<<dim3(G * B_ * T_), 64, 0, stream>>>(sbuf);
        gemm_mfma<false,false,false,false><<<dim3(4,1,G*B_),256,0,stream>>>(
            sbuf, sBTT, sTT, T_,
            vb + g0*64, 64, sTC, C_,
            attn + g0*64, 64, sTC, C_,
            nullptr,0,0,0, nullptr,nullptr, 64, T_, B_);
    }
    gemm_mfma<true,false,false,true><<<dim3(64,8,1),256,0,stream>>>(
        attn,0,0,C_,  Wo_t,0,0,C_,  src2,0,0,C_,  src,0,0,C_, nullptr,nullptr, C_, C_, 1);

    // ---- FFN block 1 (4 chunks of 512 hidden) ----
    ln512<<<dim3(B_ * T_), 64, 0, stream>>>(src2, g2, be2, xbuf);
    for (int j = 0; j < 4; j++) {
        gemm_mfma<true,true,true,false><<<dim3(64,8,1),256,0,stream>>>(
            xbuf,0,0,C_,  W1 + (long)j*512*C_,0,0,C_,  hbuf,0,0,512,
            nullptr,0,0,0,  b1 + j*512, alphap, 512, C_, 1);
        if (j == 0)
            gemm_mfma<true,true,false,true><<<dim3(64,8,1),256,0,stream>>>(
                hbuf,0,0,512,  W2 + j*512,0,0,HID_,  src3,0,0,C_,  src2,0,0,C_,
                b2, nullptr, C_, 512, 1);
        else
            gemm_mfma<true,false,false,true><<<dim3(64,8,1),256,0,stream>>>(
                hbuf,0,0,512,  W2 + j*512,0,0,HID_,  src3,0,0,C_,  src3,0,0,C_,
                nullptr, nullptr, C_, 512, 1);
    }

    // ---- spatial attention (weights only, mean over heads) ----
    ln512<<<dim3(B_ * C_), 64, 0, stream>>>(ssrc, sg, sbe, qb);
    gemm_mfma<true,false,false,false><<<dim3(64,8,1),256,0,stream>>>(
        qb,0,0,L_,  Wq_s,0,0,L_,  kb,0,0,512,  nullptr,0,0,0, nullptr,nullptr, 512, L_, 1);
    gemm_mfma<true,false,false,false><<<dim3(64,8,1),256,0,stream>>>(
        qb,0,0,L_,  Wk_s,0,0,L_,  vb,0,0,512,  nullptr,0,0,0, nullptr,nullptr, 512, L_, 1);
    for (int g0 = 0; g0 < H_; g0 += G) {
        gemm_mfma<true,false,false,false><<<dim3(4,8,G*B_),256,0,stream>>>(
            kb + g0*64, 64, (long)C_*512, 512,
            vb + g0*64, 64, (long)C_*512, 512,
            sbuf, sBCC, (long)C_*C_, C_,
            nullptr,0,0,0, nullptr,nullptr, C_, 64, B_);
        if (g0 == 0) softmax_accum512<true ><<<dim3(B_ * C_), 64, 0, stream>>>(sbuf, out_sw, G);
        else         softmax_accum512<false><<<dim3(B_ * C_), 64, 0, stream>>>(sbuf, out_sw, G);
    }

    // ---- temporal-spatial mixing ----
    ln512<<<dim3(B_ * T_), 64, 0, stream>>>(src3, tsg1, tsbe1, xbuf);
    gemm_mfma<true,false,false,true><<<dim3(4,8,16),256,0,stream>>>(
        xbuf,   0, sTC, C_,
        out_sw, 0, (long)C_*C_, C_,
        attn,   0, sTC, C_,
        src3,   0, sTC, C_,
        nullptr, nullptr, C_, C_, 16);

    // ---- FFN block 2 (final output into d_out) ----
    ln512<<<dim3(B_ * T_), 64, 0, stream>>>(attn, tsg2, tsbe2, xbuf);
    for (int j = 0; j < 4; j++) {
        gemm_mfma<true,true,true,false><<<dim3(64,8,1),256,0,stream>>>(
            xbuf,0,0,C_,  tsW1 + (long)j*512*C_,0,0,C_,  hbuf,0,0,512,
            nullptr,0,0,0,  tsb1 + j*512, alphap, 512, C_, 1);
        if (j == 0)
            gemm_mfma<true,true,false,true><<<dim3(64,8,1),256,0,stream>>>(
                hbuf,0,0,512,  tsW2 + j*512,0,0,HID_,  out_ts,0,0,C_,  attn,0,0,C_,
                tsb2, nullptr, C_, 512, 1);
        else
            gemm_mfma<true,false,false,true><<<dim3(64,8,1),256,0,stream>>>(
                hbuf,0,0,512,  tsW2 + j*512,0,0,HID_,  out_ts,0,0,C_,  out_ts,0,0,C_,
                nullptr, nullptr, C_, 512, 1);
    }
}

// Round 7
// 896.727 us; speedup vs baseline: 3.0381x; 1.0884x over previous
//
#include <hip/hip_runtime.h>

static constexpr int B_ = 16, T_ = 512, C_ = 512, L_ = 512, H_ = 8, HID_ = 2048;
static constexpr long NBT_ = (long)B_ * T_ * C_;   // 4,194,304 elements per [B,T,C] unit

typedef _Float16 half8_t __attribute__((ext_vector_type(8)));
typedef float    f32x4   __attribute__((ext_vector_type(4)));

// split fp32 -> f16 hi + f16 lo (hi+lo carries ~22 mantissa bits)
#define SPL(H, L, idx, val) { float _x = (val); _Float16 _h = (_Float16)_x; \
                              (H)[idx] = _h; (L)[idx] = (_Float16)(_x - (float)_h); }

// ---------------------------------------------------------------------------
// LayerNorm over last dim (=512). One wave per row, 8 elems/lane, shfl reduce.
// ---------------------------------------------------------------------------
__global__ __launch_bounds__(64)
void ln512(const float* __restrict__ in, const float* __restrict__ gam,
           const float* __restrict__ bet, float* __restrict__ out)
{
    const long r = blockIdx.x;
    const int lane = threadIdx.x;
    const float* rowp = in + r * 512 + lane * 8;
    float4 a = *(const float4*)rowp;
    float4 c = *(const float4*)(rowp + 4);
    float v[8] = {a.x, a.y, a.z, a.w, c.x, c.y, c.z, c.w};
    float s = 0.f;
#pragma unroll
    for (int i = 0; i < 8; i++) s += v[i];
#pragma unroll
    for (int m = 1; m < 64; m <<= 1) s += __shfl_xor(s, m);
    const float mean = s * (1.f / 512.f);
    float q = 0.f;
#pragma unroll
    for (int i = 0; i < 8; i++) { float d = v[i] - mean; q += d * d; }
#pragma unroll
    for (int m = 1; m < 64; m <<= 1) q += __shfl_xor(q, m);
    const float rstd = rsqrtf(q * (1.f / 512.f) + 1e-5f);
    float4 g0 = *(const float4*)(gam + lane * 8);
    float4 g1 = *(const float4*)(gam + lane * 8 + 4);
    float4 b0 = *(const float4*)(bet + lane * 8);
    float4 b1 = *(const float4*)(bet + lane * 8 + 4);
    float gg[8] = {g0.x, g0.y, g0.z, g0.w, g1.x, g1.y, g1.z, g1.w};
    float bb[8] = {b0.x, b0.y, b0.z, b0.w, b1.x, b1.y, b1.z, b1.w};
    float o[8];
#pragma unroll
    for (int i = 0; i < 8; i++) o[i] = (v[i] - mean) * rstd * gg[i] + bb[i];
    float* op = out + r * 512 + lane * 8;
    *(float4*)op       = make_float4(o[0], o[1], o[2], o[3]);
    *(float4*)(op + 4) = make_float4(o[4], o[5], o[6], o[7]);
}

// ---------------------------------------------------------------------------
// Spatial: softmax (scale 1/8) of nh f16 head slices + accumulate mean (1/8)
// into out (f32). sbuf slice h at sbuf + h*B*C*C halves; row r = b*C + n.
// ---------------------------------------------------------------------------
template<bool FIRST>
__global__ __launch_bounds__(64)
void softmax_accum512h(const _Float16* __restrict__ sbuf, float* __restrict__ out, int nh)
{
    const long r = blockIdx.x;
    const int lane = threadIdx.x;
    float acc[8] = {0.f,0.f,0.f,0.f,0.f,0.f,0.f,0.f};
    for (int hh = 0; hh < nh; ++hh) {
        const _Float16* rowp = sbuf + (long)hh * B_ * C_ * C_ + r * 512 + lane * 8;
        half8_t hv = *(const half8_t*)rowp;
        float v[8];
#pragma unroll
        for (int i = 0; i < 8; i++) v[i] = (float)hv[i];
        float mx = -3.0e38f;
#pragma unroll
        for (int i = 0; i < 8; i++) { v[i] *= 0.125f; mx = fmaxf(mx, v[i]); }
#pragma unroll
        for (int m = 1; m < 64; m <<= 1) mx = fmaxf(mx, __shfl_xor(mx, m));
        float s = 0.f;
#pragma unroll
        for (int i = 0; i < 8; i++) { v[i] = __expf(v[i] - mx); s += v[i]; }
#pragma unroll
        for (int m = 1; m < 64; m <<= 1) s += __shfl_xor(s, m);
        const float inv = 1.f / s;
#pragma unroll
        for (int i = 0; i < 8; i++) acc[i] += v[i] * inv;
    }
    float* op = out + r * 512 + lane * 8;
    if (FIRST) {
        *(float4*)op       = make_float4(acc[0]*0.125f, acc[1]*0.125f, acc[2]*0.125f, acc[3]*0.125f);
        *(float4*)(op + 4) = make_float4(acc[4]*0.125f, acc[5]*0.125f, acc[6]*0.125f, acc[7]*0.125f);
    } else {
        float4 e0 = *(const float4*)op;
        float4 e1 = *(const float4*)(op + 4);
        *(float4*)op       = make_float4(e0.x + acc[0]*0.125f, e0.y + acc[1]*0.125f,
                                         e0.z + acc[2]*0.125f, e0.w + acc[3]*0.125f);
        *(float4*)(op + 4) = make_float4(e1.x + acc[4]*0.125f, e1.y + acc[5]*0.125f,
                                         e1.z + acc[6]*0.125f, e1.w + acc[7]*0.125f);
    }
}

// ---------------------------------------------------------------------------
// Fused temporal flash attention. Grid (T/64, B*H), 256 thr = 4 waves.
// Per block: (b,h), 64 q-rows. K/V streamed in 64-row tiles via LDS (f16);
// online softmax in registers; P via per-wave LDS f16; V staged transposed.
// q/k/v/out layout: [B,T,C] with head slice at col h*64, HS=64.
// ---------------------------------------------------------------------------
__global__ __launch_bounds__(256)
void flash_attn(const float* __restrict__ qg, const float* __restrict__ kg,
                const float* __restrict__ vg, float* __restrict__ og)
{
    __shared__ __align__(16) _Float16 Ks [64 * 72];
    __shared__ __align__(16) _Float16 VsT[64 * 72];
    __shared__ __align__(16) _Float16 Ps [4 * 16 * 72];

    const int t    = threadIdx.x;
    const int bh   = blockIdx.y;
    const int b    = bh >> 3, h = bh & 7;
    const int q0   = blockIdx.x * 64;
    const long base = (long)b * T_ * C_ + h * 64;

    const int wave = t >> 6, lane = t & 63;
    const int fr = lane & 15;
    const int k8 = (lane >> 4) << 3;     // 0,8,16,24
    const int rq = (lane >> 4) << 2;     // C/D row base 0,4,8,12

    const int sr = t >> 2;               // staging row 0..63
    const int sc = (t & 3) << 4;         // staging col 0,16,32,48

    // Q fragments direct from global (rows q0+wave*16+fr)
    half8_t qf[2];
    {
        const float* qp = qg + base + (long)(q0 + wave * 16 + fr) * C_;
#pragma unroll
        for (int ks = 0; ks < 2; ++ks) {
            float4 u0 = *(const float4*)(qp + ks * 32 + k8);
            float4 u1 = *(const float4*)(qp + ks * 32 + k8 + 4);
            half8_t q8;
            q8[0]=(_Float16)u0.x; q8[1]=(_Float16)u0.y; q8[2]=(_Float16)u0.z; q8[3]=(_Float16)u0.w;
            q8[4]=(_Float16)u1.x; q8[5]=(_Float16)u1.y; q8[6]=(_Float16)u1.z; q8[7]=(_Float16)u1.w;
            qf[ks] = q8;
        }
    }

    f32x4 o[4];
#pragma unroll
    for (int d = 0; d < 4; ++d) o[d] = (f32x4)0.f;
    float m[4] = {-3.0e38f, -3.0e38f, -3.0e38f, -3.0e38f};
    float l[4] = {0.f, 0.f, 0.f, 0.f};

    _Float16* Pw = Ps + wave * 16 * 72;

    for (int it = 0; it < 8; ++it) {
        __syncthreads();
        // ---- stage K tile (row-major [kv][hs]) and V tile (transposed [hs][kv])
        {
            const float* kp = kg + base + (long)(it * 64 + sr) * C_ + sc;
            float4 a0 = *(const float4*)(kp);
            float4 a1 = *(const float4*)(kp + 4);
            float4 a2 = *(const float4*)(kp + 8);
            float4 a3 = *(const float4*)(kp + 12);
            half8_t h0, h1;
            h0[0]=(_Float16)a0.x; h0[1]=(_Float16)a0.y; h0[2]=(_Float16)a0.z; h0[3]=(_Float16)a0.w;
            h0[4]=(_Float16)a1.x; h0[5]=(_Float16)a1.y; h0[6]=(_Float16)a1.z; h0[7]=(_Float16)a1.w;
            h1[0]=(_Float16)a2.x; h1[1]=(_Float16)a2.y; h1[2]=(_Float16)a2.z; h1[3]=(_Float16)a2.w;
            h1[4]=(_Float16)a3.x; h1[5]=(_Float16)a3.y; h1[6]=(_Float16)a3.z; h1[7]=(_Float16)a3.w;
            *(half8_t*)&Ks[sr * 72 + sc]     = h0;
            *(half8_t*)&Ks[sr * 72 + sc + 8] = h1;

            const float* vp = vg + base + (long)(it * 64 + sr) * C_ + sc;
            float4 b0 = *(const float4*)(vp);
            float4 b1v = *(const float4*)(vp + 4);
            float4 b2 = *(const float4*)(vp + 8);
            float4 b3 = *(const float4*)(vp + 12);
            float vv[16] = {b0.x,b0.y,b0.z,b0.w, b1v.x,b1v.y,b1v.z,b1v.w,
                            b2.x,b2.y,b2.z,b2.w, b3.x,b3.y,b3.z,b3.w};
#pragma unroll
            for (int c = 0; c < 16; ++c)
                VsT[(sc + c) * 72 + sr] = (_Float16)vv[c];
        }
        __syncthreads();

        // ---- scores S = (Q K^T) * 0.125 ; C/D: row=q (rq+r), col=kv (jn*16+fr)
        f32x4 s[4];
#pragma unroll
        for (int jn = 0; jn < 4; ++jn) {
            half8_t k0 = *(const half8_t*)&Ks[(jn * 16 + fr) * 72 + k8];
            half8_t k1 = *(const half8_t*)&Ks[(jn * 16 + fr) * 72 + 32 + k8];
            f32x4 accv = (f32x4)0.f;
            accv = __builtin_amdgcn_mfma_f32_16x16x32_f16(qf[0], k0, accv, 0, 0, 0);
            accv = __builtin_amdgcn_mfma_f32_16x16x32_f16(qf[1], k1, accv, 0, 0, 0);
#pragma unroll
            for (int r = 0; r < 4; ++r) accv[r] *= 0.125f;
            s[jn] = accv;
        }

        // ---- online softmax (row reduce across 16-lane col groups)
        float sc4[4];
#pragma unroll
        for (int r = 0; r < 4; ++r) {
            float v = fmaxf(fmaxf(s[0][r], s[1][r]), fmaxf(s[2][r], s[3][r]));
            v = fmaxf(v, __shfl_xor(v, 1));
            v = fmaxf(v, __shfl_xor(v, 2));
            v = fmaxf(v, __shfl_xor(v, 4));
            v = fmaxf(v, __shfl_xor(v, 8));
            const float mn = fmaxf(m[r], v);
            sc4[r] = __expf(m[r] - mn);
            m[r] = mn;
        }
        float p[4][4];
#pragma unroll
        for (int jn = 0; jn < 4; ++jn)
#pragma unroll
            for (int r = 0; r < 4; ++r) p[jn][r] = __expf(s[jn][r] - m[r]);
#pragma unroll
        for (int r = 0; r < 4; ++r) {
            float sum = p[0][r] + p[1][r] + p[2][r] + p[3][r];
            sum += __shfl_xor(sum, 1);
            sum += __shfl_xor(sum, 2);
            sum += __shfl_xor(sum, 4);
            sum += __shfl_xor(sum, 8);
            l[r] = l[r] * sc4[r] + sum;
        }
#pragma unroll
        for (int d = 0; d < 4; ++d)
#pragma unroll
            for (int r = 0; r < 4; ++r) o[d][r] *= sc4[r];

        // ---- P -> per-wave LDS (f16), natural [q][kv] layout
#pragma unroll
        for (int jn = 0; jn < 4; ++jn)
#pragma unroll
            for (int r = 0; r < 4; ++r)
                Pw[(rq + r) * 72 + jn * 16 + fr] = (_Float16)p[jn][r];
        __syncthreads();

        // ---- O += P V  (A = P natural read, B = V^T natural read)
        half8_t pf0 = *(const half8_t*)&Pw[fr * 72 + k8];
        half8_t pf1 = *(const half8_t*)&Pw[fr * 72 + 32 + k8];
#pragma unroll
        for (int d = 0; d < 4; ++d) {
            half8_t v0 = *(const half8_t*)&VsT[(d * 16 + fr) * 72 + k8];
            half8_t v1 = *(const half8_t*)&VsT[(d * 16 + fr) * 72 + 32 + k8];
            o[d] = __builtin_amdgcn_mfma_f32_16x16x32_f16(pf0, v0, o[d], 0, 0, 0);
            o[d] = __builtin_amdgcn_mfma_f32_16x16x32_f16(pf1, v1, o[d], 0, 0, 0);
        }
    }

    // ---- normalize and write
#pragma unroll
    for (int r = 0; r < 4; ++r) {
        const float inv = 1.f / l[r];
        float* op = og + base + (long)(q0 + wave * 16 + rq + r) * C_;
#pragma unroll
        for (int d = 0; d < 4; ++d) op[d * 16 + fr] = o[d][r] * inv;
    }
}

// ---------------------------------------------------------------------------
// Split-f16 MFMA GEMM: fp32 in, fp32 (or f16 when OUT16) out.
//   TB=true : O = A @ Bm^T  (Bm [N,K] row-major)
//   TB=false: O = A @ Bm    (Bm [K,N] row-major)
// Epilogue: +bias[n], PReLU(alpha), +res.  Batched via blockIdx.z (z1*nz2+z2).
// Tile: BM=128 x BN=64 x BK=32; 256 threads = 4 waves (2x2); wave tile 64x32.
// ---------------------------------------------------------------------------
template<bool TB, bool BIAS, bool PRELU, bool RES, bool OUT16 = false>
__global__ __launch_bounds__(256)
void gemm_mfma(const float* __restrict__ A,  long sA1, long sA2, int lda,
               const float* __restrict__ Bm, long sB1, long sB2, int ldb,
               float*       __restrict__ O,  long sO1, long sO2, int ldo,
               const float* __restrict__ Rp, long sR1, long sR2, int ldr,
               const float* __restrict__ bias, const float* __restrict__ alphap,
               int N, int K, int nz2)
{
    __shared__ __align__(16) _Float16 AsH[128 * 40];
    __shared__ __align__(16) _Float16 AsL[128 * 40];
    __shared__ __align__(16) _Float16 BsH[64 * 40];
    __shared__ __align__(16) _Float16 BsL[64 * 40];

    const int t  = threadIdx.x;
    const int z  = blockIdx.z;
    const int z1 = z / nz2, z2 = z - z1 * nz2;
    const long bm = (long)blockIdx.x * 128;
    const int  bn = blockIdx.y * 64;

    const float* Ab = A  + sA1 * z1 + sA2 * z2 + bm * lda;
    const float* Bb = Bm + sB1 * z1 + sB2 * z2;

    const int ar = t >> 1;              // 0..127
    const int ak = (t & 1) << 4;        // 0,16
    const float* Ap = Ab + (long)ar * lda + ak;
    const int br = t >> 2;              // 0..63
    const int bk = (t & 3) << 3;        // 0,8,16,24
    const float* BpT = Bb + (long)(bn + br) * ldb + bk;
    const int fk = t >> 3;              // 0..31
    const int fn = (t & 7) << 2;        // 0,4,..,28
    const float* BpF = Bb + (long)fk * ldb + bn + fn;

    const int wave = t >> 6, lane = t & 63;
    const int wm = (wave >> 1) << 6;    // 0,64
    const int wn = (wave & 1) << 5;     // 0,32
    const int fr = lane & 15;
    const int k8 = (lane >> 4) << 3;    // 0,8,16,24

    f32x4 acc[4][2];
#pragma unroll
    for (int i = 0; i < 4; i++)
#pragma unroll
        for (int j = 0; j < 2; j++) acc[i][j] = (f32x4)0.f;

    const int KT = K >> 5;
    for (int kt = 0; kt < KT; ++kt) {
        if (kt) __syncthreads();
        {
            const float* p = Ap + (kt << 5);
            float4 v0 = *(const float4*)(p);
            float4 v1 = *(const float4*)(p + 4);
            float4 v2 = *(const float4*)(p + 8);
            float4 v3 = *(const float4*)(p + 12);
            half8_t h0, l0, h1, l1;
            SPL(h0, l0, 0, v0.x) SPL(h0, l0, 1, v0.y) SPL(h0, l0, 2, v0.z) SPL(h0, l0, 3, v0.w)
            SPL(h0, l0, 4, v1.x) SPL(h0, l0, 5, v1.y) SPL(h0, l0, 6, v1.z) SPL(h0, l0, 7, v1.w)
            SPL(h1, l1, 0, v2.x) SPL(h1, l1, 1, v2.y) SPL(h1, l1, 2, v2.z) SPL(h1, l1, 3, v2.w)
            SPL(h1, l1, 4, v3.x) SPL(h1, l1, 5, v3.y) SPL(h1, l1, 6, v3.z) SPL(h1, l1, 7, v3.w)
            const int o = ar * 40 + ak;
            *(half8_t*)&AsH[o]     = h0;  *(half8_t*)&AsH[o + 8] = h1;
            *(half8_t*)&AsL[o]     = l0;  *(half8_t*)&AsL[o + 8] = l1;
        }
        if (TB) {
            const float* p = BpT + (kt << 5);
            float4 v0 = *(const float4*)(p);
            float4 v1 = *(const float4*)(p + 4);
            half8_t h, l;
            SPL(h, l, 0, v0.x) SPL(h, l, 1, v0.y) SPL(h, l, 2, v0.z) SPL(h, l, 3, v0.w)
            SPL(h, l, 4, v1.x) SPL(h, l, 5, v1.y) SPL(h, l, 6, v1.z) SPL(h, l, 7, v1.w)
            const int o = br * 40 + bk;
            *(half8_t*)&BsH[o] = h;
            *(half8_t*)&BsL[o] = l;
        } else {
            const float* p = BpF + ((long)(kt << 5)) * ldb;
#pragma unroll
            for (int g = 0; g < 2; ++g) {
                const int n = fn + (g << 5);
                float4 v = *(const float4*)(p + (g << 5));
                float e[4] = {v.x, v.y, v.z, v.w};
#pragma unroll
                for (int c = 0; c < 4; ++c) {
                    const float x = (bn + n + c < N) ? e[c] : 0.f;
                    _Float16 hh = (_Float16)x;
                    BsH[(n + c) * 40 + fk] = hh;
                    BsL[(n + c) * 40 + fk] = (_Float16)(x - (float)hh);
                }
            }
        }
        __syncthreads();
        half8_t aH[4], aL[4], bH[2], bL[2];
#pragma unroll
        for (int i = 0; i < 4; ++i) {
            const int o = (wm + i * 16 + fr) * 40 + k8;
            aH[i] = *(const half8_t*)&AsH[o];
            aL[i] = *(const half8_t*)&AsL[o];
        }
#pragma unroll
        for (int j = 0; j < 2; ++j) {
            const int o = (wn + j * 16 + fr) * 40 + k8;
            bH[j] = *(const half8_t*)&BsH[o];
            bL[j] = *(const half8_t*)&BsL[o];
        }
#pragma unroll
        for (int i = 0; i < 4; ++i)
#pragma unroll
            for (int j = 0; j < 2; ++j) {
                acc[i][j] = __builtin_amdgcn_mfma_f32_16x16x32_f16(aH[i], bH[j], acc[i][j], 0, 0, 0);
                acc[i][j] = __builtin_amdgcn_mfma_f32_16x16x32_f16(aH[i], bL[j], acc[i][j], 0, 0, 0);
                acc[i][j] = __builtin_amdgcn_mfma_f32_16x16x32_f16(aL[i], bH[j], acc[i][j], 0, 0, 0);
            }
    }

    const float alpha = PRELU ? alphap[0] : 0.f;
    const float* Rb = nullptr;
    if (RES) Rb = Rp + sR1 * z1 + sR2 * z2 + bm * ldr;
    const int r4 = (lane >> 4) << 2;    // 0,4,8,12
    if (OUT16) {
        _Float16* Ob16 = (_Float16*)O + sO1 * z1 + sO2 * z2 + bm * ldo;
#pragma unroll
        for (int i = 0; i < 4; ++i)
#pragma unroll
            for (int j = 0; j < 2; ++j) {
                const int col = bn + wn + j * 16 + fr;
                if (col >= N) continue;
#pragma unroll
                for (int r = 0; r < 4; ++r) {
                    const int row = wm + i * 16 + r4 + r;
                    Ob16[(long)row * ldo + col] = (_Float16)acc[i][j][r];
                }
            }
        return;
    }
    float* Ob = O + sO1 * z1 + sO2 * z2 + bm * ldo;
#pragma unroll
    for (int i = 0; i < 4; ++i) {
#pragma unroll
        for (int j = 0; j < 2; ++j) {
            const int col = bn + wn + j * 16 + fr;
            if (col >= N) continue;
            const float bv = BIAS ? bias[col] : 0.f;
#pragma unroll
            for (int r = 0; r < 4; ++r) {
                const int row = wm + i * 16 + r4 + r;
                float x = acc[i][j][r];
                if (BIAS) x += bv;
                if (PRELU) x = (x >= 0.f) ? x : alpha * x;
                if (RES) x += Rb[(long)row * ldr + col];
                Ob[(long)row * ldo + col] = x;
            }
        }
    }
}

// ---------------------------------------------------------------------------
extern "C" void kernel_launch(void* const* d_in, const int* in_sizes, int n_in,
                              void* d_out, int out_size, void* d_ws, size_t ws_size,
                              hipStream_t stream)
{
    (void)in_sizes; (void)n_in; (void)out_size;
    const float* src    = (const float*)d_in[0];
    const float* ssrc   = (const float*)d_in[1];
    const float* Wq_t   = (const float*)d_in[2];
    const float* Wk_t   = (const float*)d_in[3];
    const float* Wv_t   = (const float*)d_in[4];
    const float* Wo_t   = (const float*)d_in[5];
    const float* Wq_s   = (const float*)d_in[6];
    const float* Wk_s   = (const float*)d_in[7];
    const float* W1     = (const float*)d_in[8];
    const float* b1     = (const float*)d_in[9];
    const float* W2     = (const float*)d_in[10];
    const float* b2     = (const float*)d_in[11];
    const float* tsW1   = (const float*)d_in[12];
    const float* tsb1   = (const float*)d_in[13];
    const float* tsW2   = (const float*)d_in[14];
    const float* tsb2   = (const float*)d_in[15];
    const float* alphap = (const float*)d_in[16];
    const float* g1     = (const float*)d_in[17];
    const float* be1    = (const float*)d_in[18];
    const float* g2     = (const float*)d_in[19];
    const float* be2    = (const float*)d_in[20];
    const float* tsg1   = (const float*)d_in[21];
    const float* tsbe1  = (const float*)d_in[22];
    const float* tsg2   = (const float*)d_in[23];
    const float* tsbe2  = (const float*)d_in[24];
    const float* sg     = (const float*)d_in[25];
    const float* sbe    = (const float*)d_in[26];

    float* ws   = (float*)d_ws;
    float* xbuf = ws;                 // LN outputs (reused)
    float* qb   = ws + 1 * NBT_;      // q   | sp
    float* kb   = ws + 2 * NBT_;      // k   | qs
    float* vb   = ws + 3 * NBT_;      // v   | ks
    float* attn = ws + 4 * NBT_;      // attn| mix_out
    float* src2 = ws + 5 * NBT_;      // post temporal residual
    float* hbuf = ws + 6 * NBT_;      // FFN hidden chunk
    float* src3 = ws + 7 * NBT_;      // post FFN1 residual
    float* out_ts = (float*)d_out;            // ts_out  [B,T,C]
    float* out_sw = (float*)d_out + NBT_;     // spatial_weights [B,C,C]

    // adaptive head-group size for spatial score buffer (f16 now; tiers kept)
    const size_t unit_b = (size_t)NBT_ * 4;
    const size_t ua = ws_size / unit_b;
    int G; float* sbuf;
    if      (ua >= 16) { G = 8; sbuf = ws + 8 * NBT_; }
    else if (ua >= 12) { G = 4; sbuf = ws + 8 * NBT_; }
    else if (ua >= 10) { G = 2; sbuf = ws + 8 * NBT_; }
    else if (ua >=  9) { G = 1; sbuf = ws + 8 * NBT_; }
    else               { G = 1; sbuf = hbuf; }   // alias: never concurrently live

    const long sTC  = (long)T_ * C_;
    const long sBCC = (long)B_ * C_ * C_;

    // ---- temporal attention block ----
    ln512<<<dim3(B_ * T_), 64, 0, stream>>>(src, g1, be1, xbuf);
    gemm_mfma<true,false,false,false><<<dim3(64,8,1),256,0,stream>>>(
        xbuf,0,0,C_,  Wq_t,0,0,C_,  qb,0,0,C_,  nullptr,0,0,0, nullptr,nullptr, C_, C_, 1);
    gemm_mfma<true,false,false,false><<<dim3(64,8,1),256,0,stream>>>(
        xbuf,0,0,C_,  Wk_t,0,0,C_,  kb,0,0,C_,  nullptr,0,0,0, nullptr,nullptr, C_, C_, 1);
    gemm_mfma<true,false,false,false><<<dim3(64,8,1),256,0,stream>>>(
        xbuf,0,0,C_,  Wv_t,0,0,C_,  vb,0,0,C_,  nullptr,0,0,0, nullptr,nullptr, C_, C_, 1);

    flash_attn<<<dim3(T_ / 64, B_ * H_), 256, 0, stream>>>(qb, kb, vb, attn);

    gemm_mfma<true,false,false,true><<<dim3(64,8,1),256,0,stream>>>(
        attn,0,0,C_,  Wo_t,0,0,C_,  src2,0,0,C_,  src,0,0,C_, nullptr,nullptr, C_, C_, 1);

    // ---- FFN block 1 (4 chunks of 512 hidden) ----
    ln512<<<dim3(B_ * T_), 64, 0, stream>>>(src2, g2, be2, xbuf);
    for (int j = 0; j < 4; j++) {
        gemm_mfma<true,true,true,false><<<dim3(64,8,1),256,0,stream>>>(
            xbuf,0,0,C_,  W1 + (long)j*512*C_,0,0,C_,  hbuf,0,0,512,
            nullptr,0,0,0,  b1 + j*512, alphap, 512, C_, 1);
        if (j == 0)
            gemm_mfma<true,true,false,true><<<dim3(64,8,1),256,0,stream>>>(
                hbuf,0,0,512,  W2 + j*512,0,0,HID_,  src3,0,0,C_,  src2,0,0,C_,
                b2, nullptr, C_, 512, 1);
        else
            gemm_mfma<true,false,false,true><<<dim3(64,8,1),256,0,stream>>>(
                hbuf,0,0,512,  W2 + j*512,0,0,HID_,  src3,0,0,C_,  src3,0,0,C_,
                nullptr, nullptr, C_, 512, 1);
    }

    // ---- spatial attention (weights only, mean over heads; f16 scores) ----
    ln512<<<dim3(B_ * C_), 64, 0, stream>>>(ssrc, sg, sbe, qb);
    gemm_mfma<true,false,false,false><<<dim3(64,8,1),256,0,stream>>>(
        qb,0,0,L_,  Wq_s,0,0,L_,  kb,0,0,512,  nullptr,0,0,0, nullptr,nullptr, 512, L_, 1);
    gemm_mfma<true,false,false,false><<<dim3(64,8,1),256,0,stream>>>(
        qb,0,0,L_,  Wk_s,0,0,L_,  vb,0,0,512,  nullptr,0,0,0, nullptr,nullptr, 512, L_, 1);
    for (int g0 = 0; g0 < H_; g0 += G) {
        gemm_mfma<true,false,false,false,true><<<dim3(4,8,G*B_),256,0,stream>>>(
            kb + g0*64, 64, (long)C_*512, 512,
            vb + g0*64, 64, (long)C_*512, 512,
            sbuf, sBCC, (long)C_*C_, C_,
            nullptr,0,0,0, nullptr,nullptr, C_, 64, B_);
        if (g0 == 0) softmax_accum512h<true ><<<dim3(B_ * C_), 64, 0, stream>>>(
            (const _Float16*)sbuf, out_sw, G);
        else         softmax_accum512h<false><<<dim3(B_ * C_), 64, 0, stream>>>(
            (const _Float16*)sbuf, out_sw, G);
    }

    // ---- temporal-spatial mixing ----
    ln512<<<dim3(B_ * T_), 64, 0, stream>>>(src3, tsg1, tsbe1, xbuf);
    gemm_mfma<true,false,false,true><<<dim3(4,8,16),256,0,stream>>>(
        xbuf,   0, sTC, C_,
        out_sw, 0, (long)C_*C_, C_,
        attn,   0, sTC, C_,
        src3,   0, sTC, C_,
        nullptr, nullptr, C_, C_, 16);

    // ---- FFN block 2 (final output into d_out) ----
    ln512<<<dim3(B_ * T_), 64, 0, stream>>>(attn, tsg2, tsbe2, xbuf);
    for (int j = 0; j < 4; j++) {
        gemm_mfma<true,true,true,false><<<dim3(64,8,1),256,0,stream>>>(
            xbuf,0,0,C_,  tsW1 + (long)j*512*C_,0,0,C_,  hbuf,0,0,512,
            nullptr,0,0,0,  tsb1 + j*512, alphap, 512, C_, 1);
        if (j == 0)
            gemm_mfma<true,true,false,true><<<dim3(64,8,1),256,0,stream>>>(
                hbuf,0,0,512,  tsW2 + j*512,0,0,HID_,  out_ts,0,0,C_,  attn,0,0,C_,
                tsb2, nullptr, C_, 512, 1);
        else
            gemm_mfma<true,false,false,true><<<dim3(64,8,1),256,0,stream>>>(
                hbuf,0,0,512,  tsW2 + j*512,0,0,HID_,  out_ts,0,0,C_,  out_ts,0,0,C_,
                nullptr, nullptr, C_, 512, 1);
    }
}

// Round 8
// 802.085 us; speedup vs baseline: 3.3965x; 1.1180x over previous
//
#include <hip/hip_runtime.h>

static constexpr int B_ = 16, T_ = 512, C_ = 512, L_ = 512, H_ = 8, HID_ = 2048;
static constexpr long NBT_ = (long)B_ * T_ * C_;   // 4,194,304 elements

typedef _Float16 half8_t __attribute__((ext_vector_type(8)));
typedef float    f32x4   __attribute__((ext_vector_type(4)));

#define SPL(H, L, idx, val) { float _x = (val); _Float16 _h = (_Float16)_x; \
                              (H)[idx] = _h; (L)[idx] = (_Float16)(_x - (float)_h); }

// ---------------------------------------------------------------------------
// Weight split: 10 arrays f32 -> f16 hi/lo. grid (512,1,10), 8 elems/thread.
// ---------------------------------------------------------------------------
struct WList {
    const float* s[10];
    _Float16*    h[10];
    _Float16*    l[10];
    int          n[10];
};

__global__ __launch_bounds__(256)
void wsplit(WList w)
{
    const int z = blockIdx.z;
    const long i = ((long)blockIdx.x * 256 + threadIdx.x) * 8;
    if (i >= w.n[z]) return;
    const float* s = w.s[z] + i;
    float4 a = *(const float4*)s;
    float4 b = *(const float4*)(s + 4);
    half8_t hh, ll;
    SPL(hh, ll, 0, a.x) SPL(hh, ll, 1, a.y) SPL(hh, ll, 2, a.z) SPL(hh, ll, 3, a.w)
    SPL(hh, ll, 4, b.x) SPL(hh, ll, 5, b.y) SPL(hh, ll, 6, b.z) SPL(hh, ll, 7, b.w)
    *(half8_t*)(w.h[z] + i) = hh;
    *(half8_t*)(w.l[z] + i) = ll;
}

// ---------------------------------------------------------------------------
// LayerNorm over 512, writing f16 hi/lo pair. One wave per row.
// ---------------------------------------------------------------------------
__global__ __launch_bounds__(64)
void ln512h(const float* __restrict__ in, const float* __restrict__ gam,
            const float* __restrict__ bet, _Float16* __restrict__ outH,
            _Float16* __restrict__ outL)
{
    const long r = blockIdx.x;
    const int lane = threadIdx.x;
    const float* rowp = in + r * 512 + lane * 8;
    float4 a = *(const float4*)rowp;
    float4 c = *(const float4*)(rowp + 4);
    float v[8] = {a.x, a.y, a.z, a.w, c.x, c.y, c.z, c.w};
    float s = 0.f;
#pragma unroll
    for (int i = 0; i < 8; i++) s += v[i];
#pragma unroll
    for (int m = 1; m < 64; m <<= 1) s += __shfl_xor(s, m);
    const float mean = s * (1.f / 512.f);
    float q = 0.f;
#pragma unroll
    for (int i = 0; i < 8; i++) { float d = v[i] - mean; q += d * d; }
#pragma unroll
    for (int m = 1; m < 64; m <<= 1) q += __shfl_xor(q, m);
    const float rstd = rsqrtf(q * (1.f / 512.f) + 1e-5f);
    float4 g0 = *(const float4*)(gam + lane * 8);
    float4 g1 = *(const float4*)(gam + lane * 8 + 4);
    float4 b0 = *(const float4*)(bet + lane * 8);
    float4 b1 = *(const float4*)(bet + lane * 8 + 4);
    float gg[8] = {g0.x, g0.y, g0.z, g0.w, g1.x, g1.y, g1.z, g1.w};
    float bb[8] = {b0.x, b0.y, b0.z, b0.w, b1.x, b1.y, b1.z, b1.w};
    half8_t hh, ll;
#pragma unroll
    for (int i = 0; i < 8; i++) {
        float o = (v[i] - mean) * rstd * gg[i] + bb[i];
        _Float16 oh = (_Float16)o;
        hh[i] = oh; ll[i] = (_Float16)(o - (float)oh);
    }
    *(half8_t*)(outH + r * 512 + lane * 8) = hh;
    *(half8_t*)(outL + r * 512 + lane * 8) = ll;
}

// ---------------------------------------------------------------------------
// Spatial: softmax (scale 1/8) of nh f16 head slices + accumulate mean (1/8)
// into out f32; when LAST also write f16 copy for the mixing GEMM.
// ---------------------------------------------------------------------------
template<bool FIRST, bool LAST>
__global__ __launch_bounds__(64)
void softmax_accum512h(const _Float16* __restrict__ sbuf, float* __restrict__ out,
                       _Float16* __restrict__ outH, int nh)
{
    const long r = blockIdx.x;
    const int lane = threadIdx.x;
    float acc[8] = {0.f,0.f,0.f,0.f,0.f,0.f,0.f,0.f};
    for (int hh = 0; hh < nh; ++hh) {
        const _Float16* rowp = sbuf + (long)hh * B_ * C_ * C_ + r * 512 + lane * 8;
        half8_t hv = *(const half8_t*)rowp;
        float v[8];
#pragma unroll
        for (int i = 0; i < 8; i++) v[i] = (float)hv[i];
        float mx = -3.0e38f;
#pragma unroll
        for (int i = 0; i < 8; i++) { v[i] *= 0.125f; mx = fmaxf(mx, v[i]); }
#pragma unroll
        for (int m = 1; m < 64; m <<= 1) mx = fmaxf(mx, __shfl_xor(mx, m));
        float s = 0.f;
#pragma unroll
        for (int i = 0; i < 8; i++) { v[i] = __expf(v[i] - mx); s += v[i]; }
#pragma unroll
        for (int m = 1; m < 64; m <<= 1) s += __shfl_xor(s, m);
        const float inv = 1.f / s;
#pragma unroll
        for (int i = 0; i < 8; i++) acc[i] += v[i] * inv;
    }
    float* op = out + r * 512 + lane * 8;
    float f[8];
    if (FIRST) {
#pragma unroll
        for (int i = 0; i < 8; i++) f[i] = acc[i] * 0.125f;
    } else {
        float4 e0 = *(const float4*)op;
        float4 e1 = *(const float4*)(op + 4);
        float pv[8] = {e0.x,e0.y,e0.z,e0.w, e1.x,e1.y,e1.z,e1.w};
#pragma unroll
        for (int i = 0; i < 8; i++) f[i] = pv[i] + acc[i] * 0.125f;
    }
    *(float4*)op       = make_float4(f[0], f[1], f[2], f[3]);
    *(float4*)(op + 4) = make_float4(f[4], f[5], f[6], f[7]);
    if (LAST) {
        half8_t hv;
#pragma unroll
        for (int i = 0; i < 8; i++) hv[i] = (_Float16)f[i];
        *(half8_t*)(outH + r * 512 + lane * 8) = hv;
    }
}

// ---------------------------------------------------------------------------
// Fused temporal flash attention, f16 in / f16 hi-lo out.
// Grid (B*H, T/64) so the 8 q-tiles of one (b,h) share an XCD (flat%8=bh%8).
// V staged transposed with kv' = kv ^ (d&48) XOR swizzle (conflict-free).
// ---------------------------------------------------------------------------
__global__ __launch_bounds__(256)
void flash_attn2(const _Float16* __restrict__ qg, const _Float16* __restrict__ kg,
                 const _Float16* __restrict__ vg, _Float16* __restrict__ oH,
                 _Float16* __restrict__ oL)
{
    __shared__ __align__(16) _Float16 Ks [64 * 72];
    __shared__ __align__(16) _Float16 VsT[64 * 72];
    __shared__ __align__(16) _Float16 Ps [4 * 16 * 72];

    const int t    = threadIdx.x;
    const int bh   = blockIdx.x;
    const int b    = bh >> 3, h = bh & 7;
    const int q0   = blockIdx.y * 64;
    const long base = (long)b * T_ * C_ + h * 64;

    const int wave = t >> 6, lane = t & 63;
    const int fr = lane & 15;
    const int k8 = (lane >> 4) << 3;     // 0,8,16,24
    const int rq = (lane >> 4) << 2;     // C/D row base 0,4,8,12

    const int sr = t >> 2;               // staging row 0..63
    const int sc = (t & 3) << 4;         // staging col 0,16,32,48

    half8_t qf[2];
    {
        const _Float16* qp = qg + base + (long)(q0 + wave * 16 + fr) * C_;
        qf[0] = *(const half8_t*)(qp + k8);
        qf[1] = *(const half8_t*)(qp + 32 + k8);
    }

    f32x4 o[4];
#pragma unroll
    for (int d = 0; d < 4; ++d) o[d] = (f32x4)0.f;
    float m[4] = {-3.0e38f, -3.0e38f, -3.0e38f, -3.0e38f};
    float l[4] = {0.f, 0.f, 0.f, 0.f};

    _Float16* Pw = Ps + wave * 16 * 72;

    for (int it = 0; it < 8; ++it) {
        __syncthreads();
        {
            const _Float16* kp = kg + base + (long)(it * 64 + sr) * C_ + sc;
            *(half8_t*)&Ks[sr * 72 + sc]     = *(const half8_t*)kp;
            *(half8_t*)&Ks[sr * 72 + sc + 8] = *(const half8_t*)(kp + 8);

            const _Float16* vp = vg + base + (long)(it * 64 + sr) * C_ + sc;
            half8_t v0 = *(const half8_t*)vp;
            half8_t v1 = *(const half8_t*)(vp + 8);
            const int kvs = sr ^ sc;     // XOR swizzle (sc = d&48 for this thread)
#pragma unroll
            for (int c = 0; c < 8; ++c) VsT[(sc + c) * 72 + kvs]     = v0[c];
#pragma unroll
            for (int c = 0; c < 8; ++c) VsT[(sc + 8 + c) * 72 + kvs] = v1[c];
        }
        __syncthreads();

        // scores S = (Q K^T) * 0.125
        f32x4 s[4];
#pragma unroll
        for (int jn = 0; jn < 4; ++jn) {
            half8_t k0 = *(const half8_t*)&Ks[(jn * 16 + fr) * 72 + k8];
            half8_t k1 = *(const half8_t*)&Ks[(jn * 16 + fr) * 72 + 32 + k8];
            f32x4 accv = (f32x4)0.f;
            accv = __builtin_amdgcn_mfma_f32_16x16x32_f16(qf[0], k0, accv, 0, 0, 0);
            accv = __builtin_amdgcn_mfma_f32_16x16x32_f16(qf[1], k1, accv, 0, 0, 0);
#pragma unroll
            for (int r = 0; r < 4; ++r) accv[r] *= 0.125f;
            s[jn] = accv;
        }

        // online softmax
        float sc4[4];
#pragma unroll
        for (int r = 0; r < 4; ++r) {
            float v = fmaxf(fmaxf(s[0][r], s[1][r]), fmaxf(s[2][r], s[3][r]));
            v = fmaxf(v, __shfl_xor(v, 1));
            v = fmaxf(v, __shfl_xor(v, 2));
            v = fmaxf(v, __shfl_xor(v, 4));
            v = fmaxf(v, __shfl_xor(v, 8));
            const float mn = fmaxf(m[r], v);
            sc4[r] = __expf(m[r] - mn);
            m[r] = mn;
        }
        float p[4][4];
#pragma unroll
        for (int jn = 0; jn < 4; ++jn)
#pragma unroll
            for (int r = 0; r < 4; ++r) p[jn][r] = __expf(s[jn][r] - m[r]);
#pragma unroll
        for (int r = 0; r < 4; ++r) {
            float sum = p[0][r] + p[1][r] + p[2][r] + p[3][r];
            sum += __shfl_xor(sum, 1);
            sum += __shfl_xor(sum, 2);
            sum += __shfl_xor(sum, 4);
            sum += __shfl_xor(sum, 8);
            l[r] = l[r] * sc4[r] + sum;
        }
#pragma unroll
        for (int d = 0; d < 4; ++d)
#pragma unroll
            for (int r = 0; r < 4; ++r) o[d][r] *= sc4[r];

        // P -> per-wave LDS (wave-local; same-wave DS ordering, no barrier)
#pragma unroll
        for (int jn = 0; jn < 4; ++jn)
#pragma unroll
            for (int r = 0; r < 4; ++r)
                Pw[(rq + r) * 72 + jn * 16 + fr] = (_Float16)p[jn][r];

        half8_t pf0 = *(const half8_t*)&Pw[fr * 72 + k8];
        half8_t pf1 = *(const half8_t*)&Pw[fr * 72 + 32 + k8];
#pragma unroll
        for (int d = 0; d < 4; ++d) {
            const int x = d << 4;   // read-side XOR = (row&48)
            half8_t v0 = *(const half8_t*)&VsT[(d * 16 + fr) * 72 + (k8 ^ x)];
            half8_t v1 = *(const half8_t*)&VsT[(d * 16 + fr) * 72 + ((32 + k8) ^ x)];
            o[d] = __builtin_amdgcn_mfma_f32_16x16x32_f16(pf0, v0, o[d], 0, 0, 0);
            o[d] = __builtin_amdgcn_mfma_f32_16x16x32_f16(pf1, v1, o[d], 0, 0, 0);
        }
    }

#pragma unroll
    for (int r = 0; r < 4; ++r) {
        const float inv = 1.f / l[r];
        const long ro = base + (long)(q0 + wave * 16 + rq + r) * C_;
#pragma unroll
        for (int d = 0; d < 4; ++d) {
            float x = o[d][r] * inv;
            _Float16 xh = (_Float16)x;
            oH[ro + d * 16 + fr] = xh;
            oL[ro + d * 16 + fr] = (_Float16)(x - (float)xh);
        }
    }
}

// ---------------------------------------------------------------------------
// f16-input MFMA GEMM (A @ B^T only). APREC/BPREC: 2=hi/lo split, 1=single.
// OMODE: 0=f32 out (+bias/prelu/res), 1=f16 single out, 2=f16 pair out.
// Tile 128x64x32, 256 thr = 4 waves (2x2), wave tile 64x32.
// ---------------------------------------------------------------------------
template<bool BIAS, bool PRELU, bool RES, int APREC, int BPREC, int OMODE>
__global__ __launch_bounds__(256)
void gemm2(const _Float16* __restrict__ AH, const _Float16* __restrict__ AL,
           long sA1, long sA2, int lda,
           const _Float16* __restrict__ BH, const _Float16* __restrict__ BL,
           long sB1, long sB2, int ldb,
           float* __restrict__ O, _Float16* __restrict__ OH, _Float16* __restrict__ OL,
           long sO1, long sO2, int ldo,
           const float* __restrict__ Rp, long sR1, long sR2, int ldr,
           const float* __restrict__ bias, const float* __restrict__ alphap,
           int K, int nz2)
{
    __shared__ __align__(16) _Float16 AsH[128 * 40];
    __shared__ __align__(16) _Float16 AsL[(APREC == 2) ? 128 * 40 : 8];
    __shared__ __align__(16) _Float16 BsH[64 * 40];
    __shared__ __align__(16) _Float16 BsL[(BPREC == 2) ? 64 * 40 : 8];

    const int t  = threadIdx.x;
    const int z  = blockIdx.z;
    const int z1 = z / nz2, z2 = z - z1 * nz2;
    const long bm = (long)blockIdx.x * 128;
    const int  bn = blockIdx.y * 64;

    const int ar = t >> 1;              // 0..127
    const int ak = (t & 1) << 4;        // 0,16
    const int br = t >> 2;              // 0..63
    const int bk = (t & 3) << 3;        // 0,8,16,24

    const _Float16* ApH = AH + sA1 * z1 + sA2 * z2 + (bm + ar) * (long)lda + ak;
    const _Float16* ApL = (APREC == 2) ? AL + sA1 * z1 + sA2 * z2 + (bm + ar) * (long)lda + ak : nullptr;
    const _Float16* BpH = BH + sB1 * z1 + sB2 * z2 + (long)(bn + br) * ldb + bk;
    const _Float16* BpL = (BPREC == 2) ? BL + sB1 * z1 + sB2 * z2 + (long)(bn + br) * ldb + bk : nullptr;

    const int wave = t >> 6, lane = t & 63;
    const int wm = (wave >> 1) << 6;    // 0,64
    const int wn = (wave & 1) << 5;     // 0,32
    const int fr = lane & 15;
    const int k8 = (lane >> 4) << 3;    // 0,8,16,24

    f32x4 acc[4][2];
#pragma unroll
    for (int i = 0; i < 4; i++)
#pragma unroll
        for (int j = 0; j < 2; j++) acc[i][j] = (f32x4)0.f;

    const int KT = K >> 5;
    for (int kt = 0; kt < KT; ++kt) {
        if (kt) __syncthreads();
        {
            const int o = ar * 40 + ak;
            *(half8_t*)&AsH[o]     = *(const half8_t*)(ApH + (kt << 5));
            *(half8_t*)&AsH[o + 8] = *(const half8_t*)(ApH + (kt << 5) + 8);
            if (APREC == 2) {
                *(half8_t*)&AsL[o]     = *(const half8_t*)(ApL + (kt << 5));
                *(half8_t*)&AsL[o + 8] = *(const half8_t*)(ApL + (kt << 5) + 8);
            }
            const int ob = br * 40 + bk;
            *(half8_t*)&BsH[ob] = *(const half8_t*)(BpH + (kt << 5));
            if (BPREC == 2)
                *(half8_t*)&BsL[ob] = *(const half8_t*)(BpL + (kt << 5));
        }
        __syncthreads();

        half8_t aH[4], aL[4], bH[2], bL[2];
#pragma unroll
        for (int i = 0; i < 4; ++i) {
            const int o = (wm + i * 16 + fr) * 40 + k8;
            aH[i] = *(const half8_t*)&AsH[o];
            if (APREC == 2) aL[i] = *(const half8_t*)&AsL[o];
        }
#pragma unroll
        for (int j = 0; j < 2; ++j) {
            const int o = (wn + j * 16 + fr) * 40 + k8;
            bH[j] = *(const half8_t*)&BsH[o];
            if (BPREC == 2) bL[j] = *(const half8_t*)&BsL[o];
        }
#pragma unroll
        for (int i = 0; i < 4; ++i)
#pragma unroll
            for (int j = 0; j < 2; ++j) {
                acc[i][j] = __builtin_amdgcn_mfma_f32_16x16x32_f16(aH[i], bH[j], acc[i][j], 0, 0, 0);
                if (BPREC == 2)
                    acc[i][j] = __builtin_amdgcn_mfma_f32_16x16x32_f16(aH[i], bL[j], acc[i][j], 0, 0, 0);
                if (APREC == 2)
                    acc[i][j] = __builtin_amdgcn_mfma_f32_16x16x32_f16(aL[i], bH[j], acc[i][j], 0, 0, 0);
            }
    }

    const float alpha = PRELU ? alphap[0] : 0.f;
    const int r4 = (lane >> 4) << 2;    // 0,4,8,12

    if (OMODE == 1) {
        _Float16* Ob = OH + sO1 * z1 + sO2 * z2 + bm * ldo;
#pragma unroll
        for (int i = 0; i < 4; ++i)
#pragma unroll
            for (int j = 0; j < 2; ++j) {
                const int col = bn + wn + j * 16 + fr;
#pragma unroll
                for (int r = 0; r < 4; ++r)
                    Ob[(long)(wm + i * 16 + r4 + r) * ldo + col] = (_Float16)acc[i][j][r];
            }
        return;
    }
    if (OMODE == 2) {
        _Float16* ObH = OH + sO1 * z1 + sO2 * z2 + bm * ldo;
        _Float16* ObL = OL + sO1 * z1 + sO2 * z2 + bm * ldo;
#pragma unroll
        for (int i = 0; i < 4; ++i)
#pragma unroll
            for (int j = 0; j < 2; ++j) {
                const int col = bn + wn + j * 16 + fr;
                const float bv = BIAS ? bias[col] : 0.f;
#pragma unroll
                for (int r = 0; r < 4; ++r) {
                    float x = acc[i][j][r];
                    if (BIAS) x += bv;
                    if (PRELU) x = (x >= 0.f) ? x : alpha * x;
                    _Float16 xh = (_Float16)x;
                    const long idx = (long)(wm + i * 16 + r4 + r) * ldo + col;
                    ObH[idx] = xh;
                    ObL[idx] = (_Float16)(x - (float)xh);
                }
            }
        return;
    }
    float* Ob = O + sO1 * z1 + sO2 * z2 + bm * ldo;
    const float* Rb = RES ? Rp + sR1 * z1 + sR2 * z2 + bm * ldr : nullptr;
#pragma unroll
    for (int i = 0; i < 4; ++i)
#pragma unroll
        for (int j = 0; j < 2; ++j) {
            const int col = bn + wn + j * 16 + fr;
            const float bv = BIAS ? bias[col] : 0.f;
#pragma unroll
            for (int r = 0; r < 4; ++r) {
                const int row = wm + i * 16 + r4 + r;
                float x = acc[i][j][r];
                if (BIAS) x += bv;
                if (PRELU) x = (x >= 0.f) ? x : alpha * x;
                if (RES) x += Rb[(long)row * ldr + col];
                Ob[(long)row * ldo + col] = x;
            }
        }
}

// ---------------------------------------------------------------------------
extern "C" void kernel_launch(void* const* d_in, const int* in_sizes, int n_in,
                              void* d_out, int out_size, void* d_ws, size_t ws_size,
                              hipStream_t stream)
{
    (void)in_sizes; (void)n_in; (void)out_size;
    const float* src    = (const float*)d_in[0];
    const float* ssrc   = (const float*)d_in[1];
    const float* Wq_t   = (const float*)d_in[2];
    const float* Wk_t   = (const float*)d_in[3];
    const float* Wv_t   = (const float*)d_in[4];
    const float* Wo_t   = (const float*)d_in[5];
    const float* Wq_s   = (const float*)d_in[6];
    const float* Wk_s   = (const float*)d_in[7];
    const float* W1     = (const float*)d_in[8];
    const float* b1     = (const float*)d_in[9];
    const float* W2     = (const float*)d_in[10];
    const float* b2     = (const float*)d_in[11];
    const float* tsW1   = (const float*)d_in[12];
    const float* tsb1   = (const float*)d_in[13];
    const float* tsW2   = (const float*)d_in[14];
    const float* tsb2   = (const float*)d_in[15];
    const float* alphap = (const float*)d_in[16];
    const float* g1     = (const float*)d_in[17];
    const float* be1    = (const float*)d_in[18];
    const float* g2     = (const float*)d_in[19];
    const float* be2    = (const float*)d_in[20];
    const float* tsg1   = (const float*)d_in[21];
    const float* tsbe1  = (const float*)d_in[22];
    const float* tsg2   = (const float*)d_in[23];
    const float* tsbe2  = (const float*)d_in[24];
    const float* sg     = (const float*)d_in[25];
    const float* sbe    = (const float*)d_in[26];

    const long U = NBT_;
    float* ws     = (float*)d_ws;
    float* src2   = ws;               // f32
    float* src3   = ws + U;           // f32
    float* mixout = ws + 2 * U;       // f32
    float* out_ts = (float*)d_out;
    float* out_sw = (float*)d_out + U;

    _Float16* hb = (_Float16*)(ws + 3 * U);   // half-unit region (U halves each)
    _Float16* xbufH = hb;          _Float16* xbufL = hb + U;
    _Float16* attnH = hb + 2 * U;  _Float16* attnL = hb + 3 * U;
    _Float16* hbufH = hb + 4 * U;  _Float16* hbufL = hb + 5 * U;
    _Float16* qh    = hb + 6 * U;
    _Float16* kh    = hb + 7 * U;
    _Float16* vh    = hb + 8 * U;
    _Float16* qsh   = hb + 9 * U;
    _Float16* ksh   = hb + 10 * U;
    _Float16* swH   = hb + 11 * U;
    _Float16* wb    = hb + 12 * U;    // weights: 11.54M halves < 3U halves

    // weight f16 buffers
    const int NS = 262144, NB = 1048576;
    _Float16* WqH  = wb;              _Float16* WqL  = wb + NS;
    _Float16* WkH  = wb + 2*NS;       _Float16* WkL  = wb + 3*NS;
    _Float16* WvH  = wb + 4*NS;       _Float16* WvL  = wb + 5*NS;
    _Float16* WoH  = wb + 6*NS;       _Float16* WoL  = wb + 7*NS;
    _Float16* WqsH = wb + 8*NS;       _Float16* WqsL = wb + 9*NS;
    _Float16* WksH = wb + 10*NS;      _Float16* WksL = wb + 11*NS;
    _Float16* bigb = wb + 12*NS;
    _Float16* W1H  = bigb;            _Float16* W1L  = bigb + NB;
    _Float16* W2H  = bigb + 2*NB;     _Float16* W2L  = bigb + 3*NB;
    _Float16* tW1H = bigb + 4*NB;     _Float16* tW1L = bigb + 5*NB;
    _Float16* tW2H = bigb + 6*NB;     _Float16* tW2L = bigb + 7*NB;

    // spatial score buffer tiers (f16, U halves per head slice)
    const size_t uaF = ws_size / ((size_t)U * 4);
    int G; _Float16* sbuf;
    if      (uaF >= 15) { G = 8; sbuf = hb + 15 * U; }
    else if (uaF >= 13) { G = 4; sbuf = hb + 15 * U; }
    else if (uaF >= 12) { G = 2; sbuf = hb + 15 * U; }
    else if (uaF >= 11) { G = 1; sbuf = hb + 15 * U; }
    else                { G = 2; sbuf = qh; }   // temporal q/k/v dead during spatial

    // ---- split weights ----
    WList wl;
    wl.s[0]=Wq_t; wl.s[1]=Wk_t; wl.s[2]=Wv_t; wl.s[3]=Wo_t; wl.s[4]=Wq_s; wl.s[5]=Wk_s;
    wl.s[6]=W1;   wl.s[7]=W2;   wl.s[8]=tsW1; wl.s[9]=tsW2;
    wl.h[0]=WqH; wl.h[1]=WkH; wl.h[2]=WvH; wl.h[3]=WoH; wl.h[4]=WqsH; wl.h[5]=WksH;
    wl.h[6]=W1H; wl.h[7]=W2H; wl.h[8]=tW1H; wl.h[9]=tW2H;
    wl.l[0]=WqL; wl.l[1]=WkL; wl.l[2]=WvL; wl.l[3]=WoL; wl.l[4]=WqsL; wl.l[5]=WksL;
    wl.l[6]=W1L; wl.l[7]=W2L; wl.l[8]=tW1L; wl.l[9]=tW2L;
    for (int i = 0; i < 6; i++) wl.n[i] = NS;
    for (int i = 6; i < 10; i++) wl.n[i] = NB;
    wsplit<<<dim3(512, 1, 10), 256, 0, stream>>>(wl);

    const long sTC  = (long)T_ * C_;
    const long sCC  = (long)C_ * C_;
    const long sBCC = (long)B_ * sCC;
    const float* nfp = nullptr; _Float16* nhp = nullptr; float* nwp = nullptr;

    // ---- temporal attention ----
    ln512h<<<dim3(B_ * T_), 64, 0, stream>>>(src, g1, be1, xbufH, xbufL);
    gemm2<false,false,false,2,2,1><<<dim3(64,8,1),256,0,stream>>>(
        xbufH,xbufL,0,0,C_,  WqH,WqL,0,0,C_,  nwp,qh,nhp,0,0,C_,
        nfp,0,0,0, nfp,nfp, C_, 1);
    gemm2<false,false,false,2,2,1><<<dim3(64,8,1),256,0,stream>>>(
        xbufH,xbufL,0,0,C_,  WkH,WkL,0,0,C_,  nwp,kh,nhp,0,0,C_,
        nfp,0,0,0, nfp,nfp, C_, 1);
    gemm2<false,false,false,2,2,1><<<dim3(64,8,1),256,0,stream>>>(
        xbufH,xbufL,0,0,C_,  WvH,WvL,0,0,C_,  nwp,vh,nhp,0,0,C_,
        nfp,0,0,0, nfp,nfp, C_, 1);

    flash_attn2<<<dim3(B_ * H_, T_ / 64), 256, 0, stream>>>(qh, kh, vh, attnH, attnL);

    gemm2<false,false,true,2,2,0><<<dim3(64,8,1),256,0,stream>>>(
        attnH,attnL,0,0,C_,  WoH,WoL,0,0,C_,  src2,nhp,nhp,0,0,C_,
        src,0,0,C_, nfp,nfp, C_, 1);

    // ---- FFN block 1 ----
    ln512h<<<dim3(B_ * T_), 64, 0, stream>>>(src2, g2, be2, xbufH, xbufL);
    for (int j = 0; j < 4; j++) {
        gemm2<true,true,false,2,2,2><<<dim3(64,8,1),256,0,stream>>>(
            xbufH,xbufL,0,0,C_,  W1H + (long)j*512*C_, W1L + (long)j*512*C_,0,0,C_,
            nwp,hbufH,hbufL,0,0,512,  nfp,0,0,0,  b1 + j*512, alphap, C_, 1);
        if (j == 0)
            gemm2<true,false,true,2,2,0><<<dim3(64,8,1),256,0,stream>>>(
                hbufH,hbufL,0,0,512,  W2H + j*512, W2L + j*512,0,0,HID_,
                src3,nhp,nhp,0,0,C_,  src2,0,0,C_,  b2, nfp, 512, 1);
        else
            gemm2<false,false,true,2,2,0><<<dim3(64,8,1),256,0,stream>>>(
                hbufH,hbufL,0,0,512,  W2H + j*512, W2L + j*512,0,0,HID_,
                src3,nhp,nhp,0,0,C_,  src3,0,0,C_,  nfp, nfp, 512, 1);
    }

    // ---- spatial attention (weights only, mean over heads) ----
    ln512h<<<dim3(B_ * C_), 64, 0, stream>>>(ssrc, sg, sbe, xbufH, xbufL);
    gemm2<false,false,false,2,2,1><<<dim3(64,8,1),256,0,stream>>>(
        xbufH,xbufL,0,0,L_,  WqsH,WqsL,0,0,L_,  nwp,qsh,nhp,0,0,512,
        nfp,0,0,0, nfp,nfp, L_, 1);
    gemm2<false,false,false,2,2,1><<<dim3(64,8,1),256,0,stream>>>(
        xbufH,xbufL,0,0,L_,  WksH,WksL,0,0,L_,  nwp,ksh,nhp,0,0,512,
        nfp,0,0,0, nfp,nfp, L_, 1);
    for (int g0 = 0; g0 < H_; g0 += G) {
        gemm2<false,false,false,1,1,1><<<dim3(4,8,G*B_),256,0,stream>>>(
            qsh + g0*64, nhp, 64, (long)C_*512, 512,
            ksh + g0*64, nhp, 64, (long)C_*512, 512,
            nwp, sbuf, nhp, sBCC, sCC, C_,
            nfp,0,0,0, nfp,nfp, 64, B_);
        const bool first = (g0 == 0), last = (g0 + G == H_);
        if (first && last)
            softmax_accum512h<true,true ><<<dim3(B_ * C_), 64, 0, stream>>>(sbuf, out_sw, swH, G);
        else if (first)
            softmax_accum512h<true,false><<<dim3(B_ * C_), 64, 0, stream>>>(sbuf, out_sw, swH, G);
        else if (last)
            softmax_accum512h<false,true><<<dim3(B_ * C_), 64, 0, stream>>>(sbuf, out_sw, swH, G);
        else
            softmax_accum512h<false,false><<<dim3(B_ * C_), 64, 0, stream>>>(sbuf, out_sw, swH, G);
    }

    // ---- temporal-spatial mixing ----
    ln512h<<<dim3(B_ * T_), 64, 0, stream>>>(src3, tsg1, tsbe1, xbufH, xbufL);
    gemm2<false,false,true,2,1,0><<<dim3(4,8,16),256,0,stream>>>(
        xbufH,xbufL, 0, sTC, C_,
        swH, nhp, 0, sCC, C_,
        mixout,nhp,nhp, 0, sTC, C_,
        src3, 0, sTC, C_,
        nfp, nfp, C_, 16);

    // ---- FFN block 2 (into d_out) ----
    ln512h<<<dim3(B_ * T_), 64, 0, stream>>>(mixout, tsg2, tsbe2, xbufH, xbufL);
    for (int j = 0; j < 4; j++) {
        gemm2<true,true,false,2,2,2><<<dim3(64,8,1),256,0,stream>>>(
            xbufH,xbufL,0,0,C_,  tW1H + (long)j*512*C_, tW1L + (long)j*512*C_,0,0,C_,
            nwp,hbufH,hbufL,0,0,512,  nfp,0,0,0,  tsb1 + j*512, alphap, C_, 1);
        if (j == 0)
            gemm2<true,false,true,2,2,0><<<dim3(64,8,1),256,0,stream>>>(
                hbufH,hbufL,0,0,512,  tW2H + j*512, tW2L + j*512,0,0,HID_,
                out_ts,nhp,nhp,0,0,C_,  mixout,0,0,C_,  tsb2, nfp, 512, 1);
        else
            gemm2<false,false,true,2,2,0><<<dim3(64,8,1),256,0,stream>>>(
                hbufH,hbufL,0,0,512,  tW2H + j*512, tW2L + j*512,0,0,HID_,
                out_ts,nhp,nhp,0,0,C_,  out_ts,0,0,C_,  nfp, nfp, 512, 1);
    }
}

// Round 9
// 568.944 us; speedup vs baseline: 4.7884x; 1.4098x over previous
//
#include <hip/hip_runtime.h>

static constexpr int B_ = 16, T_ = 512, C_ = 512, L_ = 512, H_ = 8, HID_ = 2048;
static constexpr long NBT_ = (long)B_ * T_ * C_;   // 4,194,304 elements

typedef _Float16 half8_t __attribute__((ext_vector_type(8)));
typedef float    f32x4   __attribute__((ext_vector_type(4)));

// ---------------------------------------------------------------------------
// Weight convert: 10 arrays f32 -> f16 single. grid (512,1,10), 8 elems/thr.
// Precision note: f16 weight quantization (rel 2^-11) contributes ~1e-3 abs
// per GEMM stage (f32 accumulate) — far below the 0.0156 tolerance floor
// measured on the exact-fp32 baseline (round 3).
// ---------------------------------------------------------------------------
struct WList {
    const float* s[10];
    _Float16*    h[10];
    int          n[10];
};

__global__ __launch_bounds__(256)
void wconv(WList w)
{
    const int z = blockIdx.z;
    const long i = ((long)blockIdx.x * 256 + threadIdx.x) * 8;
    if (i >= w.n[z]) return;
    const float* s = w.s[z] + i;
    float4 a = *(const float4*)s;
    float4 b = *(const float4*)(s + 4);
    half8_t hh;
    hh[0]=(_Float16)a.x; hh[1]=(_Float16)a.y; hh[2]=(_Float16)a.z; hh[3]=(_Float16)a.w;
    hh[4]=(_Float16)b.x; hh[5]=(_Float16)b.y; hh[6]=(_Float16)b.z; hh[7]=(_Float16)b.w;
    *(half8_t*)(w.h[z] + i) = hh;
}

// ---------------------------------------------------------------------------
// LayerNorm over 512, f32 in -> f16 out. One wave per row.
// ---------------------------------------------------------------------------
__global__ __launch_bounds__(64)
void ln512s(const float* __restrict__ in, const float* __restrict__ gam,
            const float* __restrict__ bet, _Float16* __restrict__ out)
{
    const long r = blockIdx.x;
    const int lane = threadIdx.x;
    const float* rowp = in + r * 512 + lane * 8;
    float4 a = *(const float4*)rowp;
    float4 c = *(const float4*)(rowp + 4);
    float v[8] = {a.x, a.y, a.z, a.w, c.x, c.y, c.z, c.w};
    float s = 0.f;
#pragma unroll
    for (int i = 0; i < 8; i++) s += v[i];
#pragma unroll
    for (int m = 1; m < 64; m <<= 1) s += __shfl_xor(s, m);
    const float mean = s * (1.f / 512.f);
    float q = 0.f;
#pragma unroll
    for (int i = 0; i < 8; i++) { float d = v[i] - mean; q += d * d; }
#pragma unroll
    for (int m = 1; m < 64; m <<= 1) q += __shfl_xor(q, m);
    const float rstd = rsqrtf(q * (1.f / 512.f) + 1e-5f);
    float4 g0 = *(const float4*)(gam + lane * 8);
    float4 g1 = *(const float4*)(gam + lane * 8 + 4);
    float4 b0 = *(const float4*)(bet + lane * 8);
    float4 b1 = *(const float4*)(bet + lane * 8 + 4);
    float gg[8] = {g0.x, g0.y, g0.z, g0.w, g1.x, g1.y, g1.z, g1.w};
    float bb[8] = {b0.x, b0.y, b0.z, b0.w, b1.x, b1.y, b1.z, b1.w};
    half8_t hh;
#pragma unroll
    for (int i = 0; i < 8; i++)
        hh[i] = (_Float16)((v[i] - mean) * rstd * gg[i] + bb[i]);
    *(half8_t*)(out + r * 512 + lane * 8) = hh;
}

// ---------------------------------------------------------------------------
// Spatial: softmax (scale 1/8) of nh f16 head slices + accumulate mean (1/8)
// into out f32; when LAST also write f16 copy for the mixing GEMM.
// ---------------------------------------------------------------------------
template<bool FIRST, bool LAST>
__global__ __launch_bounds__(64)
void softmax_accum512h(const _Float16* __restrict__ sbuf, float* __restrict__ out,
                       _Float16* __restrict__ outH, int nh)
{
    const long r = blockIdx.x;
    const int lane = threadIdx.x;
    float acc[8] = {0.f,0.f,0.f,0.f,0.f,0.f,0.f,0.f};
    for (int hh = 0; hh < nh; ++hh) {
        const _Float16* rowp = sbuf + (long)hh * B_ * C_ * C_ + r * 512 + lane * 8;
        half8_t hv = *(const half8_t*)rowp;
        float v[8];
#pragma unroll
        for (int i = 0; i < 8; i++) v[i] = (float)hv[i];
        float mx = -3.0e38f;
#pragma unroll
        for (int i = 0; i < 8; i++) { v[i] *= 0.125f; mx = fmaxf(mx, v[i]); }
#pragma unroll
        for (int m = 1; m < 64; m <<= 1) mx = fmaxf(mx, __shfl_xor(mx, m));
        float s = 0.f;
#pragma unroll
        for (int i = 0; i < 8; i++) { v[i] = __expf(v[i] - mx); s += v[i]; }
#pragma unroll
        for (int m = 1; m < 64; m <<= 1) s += __shfl_xor(s, m);
        const float inv = 1.f / s;
#pragma unroll
        for (int i = 0; i < 8; i++) acc[i] += v[i] * inv;
    }
    float* op = out + r * 512 + lane * 8;
    float f[8];
    if (FIRST) {
#pragma unroll
        for (int i = 0; i < 8; i++) f[i] = acc[i] * 0.125f;
    } else {
        float4 e0 = *(const float4*)op;
        float4 e1 = *(const float4*)(op + 4);
        float pv[8] = {e0.x,e0.y,e0.z,e0.w, e1.x,e1.y,e1.z,e1.w};
#pragma unroll
        for (int i = 0; i < 8; i++) f[i] = pv[i] + acc[i] * 0.125f;
    }
    *(float4*)op       = make_float4(f[0], f[1], f[2], f[3]);
    *(float4*)(op + 4) = make_float4(f[4], f[5], f[6], f[7]);
    if (LAST) {
        half8_t hv;
#pragma unroll
        for (int i = 0; i < 8; i++) hv[i] = (_Float16)f[i];
        *(half8_t*)(outH + r * 512 + lane * 8) = hv;
    }
}

// ---------------------------------------------------------------------------
// Fused temporal flash attention, f16 in (fused qkv buffer, row stride ldq)
// / f16 out (stride C_). Grid (B*H, T/64) for per-(b,h) XCD/L2 locality.
// V staged transposed with kv' = kv ^ (d&48) XOR swizzle (conflict-free).
// ---------------------------------------------------------------------------
__global__ __launch_bounds__(256)
void flash_attn3(const _Float16* __restrict__ qg, const _Float16* __restrict__ kg,
                 const _Float16* __restrict__ vg, _Float16* __restrict__ oH, int ldq)
{
    __shared__ __align__(16) _Float16 Ks [64 * 72];
    __shared__ __align__(16) _Float16 VsT[64 * 72];
    __shared__ __align__(16) _Float16 Ps [4 * 16 * 72];

    const int t    = threadIdx.x;
    const int bh   = blockIdx.x;
    const int b    = bh >> 3, h = bh & 7;
    const int q0   = blockIdx.y * 64;
    const long baseQ = (long)b * T_ * ldq + h * 64;
    const long baseO = (long)b * T_ * C_ + h * 64;

    const int wave = t >> 6, lane = t & 63;
    const int fr = lane & 15;
    const int k8 = (lane >> 4) << 3;     // 0,8,16,24
    const int rq = (lane >> 4) << 2;     // C/D row base 0,4,8,12

    const int sr = t >> 2;               // staging row 0..63
    const int sc = (t & 3) << 4;         // staging col 0,16,32,48

    half8_t qf[2];
    {
        const _Float16* qp = qg + baseQ + (long)(q0 + wave * 16 + fr) * ldq;
        qf[0] = *(const half8_t*)(qp + k8);
        qf[1] = *(const half8_t*)(qp + 32 + k8);
    }

    f32x4 o[4];
#pragma unroll
    for (int d = 0; d < 4; ++d) o[d] = (f32x4)0.f;
    float m[4] = {-3.0e38f, -3.0e38f, -3.0e38f, -3.0e38f};
    float l[4] = {0.f, 0.f, 0.f, 0.f};

    _Float16* Pw = Ps + wave * 16 * 72;

    for (int it = 0; it < 8; ++it) {
        __syncthreads();
        {
            const _Float16* kp = kg + baseQ + (long)(it * 64 + sr) * ldq + sc;
            *(half8_t*)&Ks[sr * 72 + sc]     = *(const half8_t*)kp;
            *(half8_t*)&Ks[sr * 72 + sc + 8] = *(const half8_t*)(kp + 8);

            const _Float16* vp = vg + baseQ + (long)(it * 64 + sr) * ldq + sc;
            half8_t v0 = *(const half8_t*)vp;
            half8_t v1 = *(const half8_t*)(vp + 8);
            const int kvs = sr ^ sc;     // XOR swizzle
#pragma unroll
            for (int c = 0; c < 8; ++c) VsT[(sc + c) * 72 + kvs]     = v0[c];
#pragma unroll
            for (int c = 0; c < 8; ++c) VsT[(sc + 8 + c) * 72 + kvs] = v1[c];
        }
        __syncthreads();

        // scores S = (Q K^T) * 0.125
        f32x4 s[4];
#pragma unroll
        for (int jn = 0; jn < 4; ++jn) {
            half8_t k0 = *(const half8_t*)&Ks[(jn * 16 + fr) * 72 + k8];
            half8_t k1 = *(const half8_t*)&Ks[(jn * 16 + fr) * 72 + 32 + k8];
            f32x4 accv = (f32x4)0.f;
            accv = __builtin_amdgcn_mfma_f32_16x16x32_f16(qf[0], k0, accv, 0, 0, 0);
            accv = __builtin_amdgcn_mfma_f32_16x16x32_f16(qf[1], k1, accv, 0, 0, 0);
#pragma unroll
            for (int r = 0; r < 4; ++r) accv[r] *= 0.125f;
            s[jn] = accv;
        }

        // online softmax
        float sc4[4];
#pragma unroll
        for (int r = 0; r < 4; ++r) {
            float v = fmaxf(fmaxf(s[0][r], s[1][r]), fmaxf(s[2][r], s[3][r]));
            v = fmaxf(v, __shfl_xor(v, 1));
            v = fmaxf(v, __shfl_xor(v, 2));
            v = fmaxf(v, __shfl_xor(v, 4));
            v = fmaxf(v, __shfl_xor(v, 8));
            const float mn = fmaxf(m[r], v);
            sc4[r] = __expf(m[r] - mn);
            m[r] = mn;
        }
        float p[4][4];
#pragma unroll
        for (int jn = 0; jn < 4; ++jn)
#pragma unroll
            for (int r = 0; r < 4; ++r) p[jn][r] = __expf(s[jn][r] - m[r]);
#pragma unroll
        for (int r = 0; r < 4; ++r) {
            float sum = p[0][r] + p[1][r] + p[2][r] + p[3][r];
            sum += __shfl_xor(sum, 1);
            sum += __shfl_xor(sum, 2);
            sum += __shfl_xor(sum, 4);
            sum += __shfl_xor(sum, 8);
            l[r] = l[r] * sc4[r] + sum;
        }
#pragma unroll
        for (int d = 0; d < 4; ++d)
#pragma unroll
            for (int r = 0; r < 4; ++r) o[d][r] *= sc4[r];

        // P -> per-wave LDS (wave-local; same-wave DS ordering, no barrier)
#pragma unroll
        for (int jn = 0; jn < 4; ++jn)
#pragma unroll
            for (int r = 0; r < 4; ++r)
                Pw[(rq + r) * 72 + jn * 16 + fr] = (_Float16)p[jn][r];

        half8_t pf0 = *(const half8_t*)&Pw[fr * 72 + k8];
        half8_t pf1 = *(const half8_t*)&Pw[fr * 72 + 32 + k8];
#pragma unroll
        for (int d = 0; d < 4; ++d) {
            const int x = d << 4;   // read-side XOR = (row&48)
            half8_t v0 = *(const half8_t*)&VsT[(d * 16 + fr) * 72 + (k8 ^ x)];
            half8_t v1 = *(const half8_t*)&VsT[(d * 16 + fr) * 72 + ((32 + k8) ^ x)];
            o[d] = __builtin_amdgcn_mfma_f32_16x16x32_f16(pf0, v0, o[d], 0, 0, 0);
            o[d] = __builtin_amdgcn_mfma_f32_16x16x32_f16(pf1, v1, o[d], 0, 0, 0);
        }
    }

#pragma unroll
    for (int r = 0; r < 4; ++r) {
        const float inv = 1.f / l[r];
        const long ro = baseO + (long)(q0 + wave * 16 + rq + r) * C_;
#pragma unroll
        for (int d = 0; d < 4; ++d)
            oH[ro + d * 16 + fr] = (_Float16)(o[d][r] * inv);
    }
}

// ---------------------------------------------------------------------------
// Single-f16 MFMA GEMM, O = A @ B^T (B is [N,K] row-major), f32 accumulate.
// OMODE: 0 = f32 out (+bias/prelu/res), 1 = f16 out (+bias/prelu).
// Tile 128x64x64 (BK=64), 256 thr = 4 waves (2x2), wave tile 64x32.
// Batched via blockIdx.z (z1 = z/nz2, z2 = z%nz2).
// ---------------------------------------------------------------------------
template<bool BIAS, bool PRELU, bool RES, int OMODE>
__global__ __launch_bounds__(256)
void gemm3(const _Float16* __restrict__ AH, long sA1, long sA2, int lda,
           const _Float16* __restrict__ BH, long sB1, long sB2, int ldb,
           float* __restrict__ O, _Float16* __restrict__ OH,
           long sO1, long sO2, int ldo,
           const float* __restrict__ Rp, long sR1, long sR2, int ldr,
           const float* __restrict__ bias, const float* __restrict__ alphap,
           int K, int nz2)
{
    __shared__ __align__(16) _Float16 As[128 * 72];
    __shared__ __align__(16) _Float16 Bs[64 * 72];

    const int t  = threadIdx.x;
    const int z  = blockIdx.z;
    const int z1 = z / nz2, z2 = z - z1 * nz2;
    const long bm = (long)blockIdx.x * 128;
    const int  bn = blockIdx.y * 64;

    const int ar = t >> 1;              // 0..127
    const int ak = (t & 1) << 5;        // 0,32
    const int br = t >> 2;              // 0..63
    const int bk = (t & 3) << 4;        // 0,16,32,48

    const _Float16* Ap = AH + sA1 * z1 + sA2 * z2 + (bm + ar) * (long)lda + ak;
    const _Float16* Bp = BH + sB1 * z1 + sB2 * z2 + (long)(bn + br) * ldb + bk;

    const int wave = t >> 6, lane = t & 63;
    const int wm = (wave >> 1) << 6;    // 0,64
    const int wn = (wave & 1) << 5;     // 0,32
    const int fr = lane & 15;
    const int k8 = (lane >> 4) << 3;    // 0,8,16,24

    f32x4 acc[4][2];
#pragma unroll
    for (int i = 0; i < 4; i++)
#pragma unroll
        for (int j = 0; j < 2; j++) acc[i][j] = (f32x4)0.f;

    const int KT = K >> 6;
    for (int kt = 0; kt < KT; ++kt) {
        if (kt) __syncthreads();
        {
            const _Float16* p = Ap + (kt << 6);
            const int o = ar * 72 + ak;
            *(half8_t*)&As[o]      = *(const half8_t*)(p);
            *(half8_t*)&As[o + 8]  = *(const half8_t*)(p + 8);
            *(half8_t*)&As[o + 16] = *(const half8_t*)(p + 16);
            *(half8_t*)&As[o + 24] = *(const half8_t*)(p + 24);
            const _Float16* q = Bp + (kt << 6);
            const int ob = br * 72 + bk;
            *(half8_t*)&Bs[ob]     = *(const half8_t*)(q);
            *(half8_t*)&Bs[ob + 8] = *(const half8_t*)(q + 8);
        }
        __syncthreads();

        half8_t a[4][2], b[2][2];
#pragma unroll
        for (int i = 0; i < 4; ++i)
#pragma unroll
            for (int ks = 0; ks < 2; ++ks)
                a[i][ks] = *(const half8_t*)&As[(wm + i * 16 + fr) * 72 + ks * 32 + k8];
#pragma unroll
        for (int j = 0; j < 2; ++j)
#pragma unroll
            for (int ks = 0; ks < 2; ++ks)
                b[j][ks] = *(const half8_t*)&Bs[(wn + j * 16 + fr) * 72 + ks * 32 + k8];
#pragma unroll
        for (int i = 0; i < 4; ++i)
#pragma unroll
            for (int j = 0; j < 2; ++j) {
                acc[i][j] = __builtin_amdgcn_mfma_f32_16x16x32_f16(a[i][0], b[j][0], acc[i][j], 0, 0, 0);
                acc[i][j] = __builtin_amdgcn_mfma_f32_16x16x32_f16(a[i][1], b[j][1], acc[i][j], 0, 0, 0);
            }
    }

    const float alpha = PRELU ? alphap[0] : 0.f;
    const int r4 = (lane >> 4) << 2;    // 0,4,8,12

    if (OMODE == 1) {
        _Float16* Ob = OH + sO1 * z1 + sO2 * z2 + bm * ldo;
#pragma unroll
        for (int i = 0; i < 4; ++i)
#pragma unroll
            for (int j = 0; j < 2; ++j) {
                const int col = bn + wn + j * 16 + fr;
                const float bv = BIAS ? bias[col] : 0.f;
#pragma unroll
                for (int r = 0; r < 4; ++r) {
                    float x = acc[i][j][r];
                    if (BIAS) x += bv;
                    if (PRELU) x = (x >= 0.f) ? x : alpha * x;
                    Ob[(long)(wm + i * 16 + r4 + r) * ldo + col] = (_Float16)x;
                }
            }
        return;
    }
    float* Ob = O + sO1 * z1 + sO2 * z2 + bm * ldo;
    const float* Rb = RES ? Rp + sR1 * z1 + sR2 * z2 + bm * ldr : nullptr;
#pragma unroll
    for (int i = 0; i < 4; ++i)
#pragma unroll
        for (int j = 0; j < 2; ++j) {
            const int col = bn + wn + j * 16 + fr;
            const float bv = BIAS ? bias[col] : 0.f;
#pragma unroll
            for (int r = 0; r < 4; ++r) {
                const int row = wm + i * 16 + r4 + r;
                float x = acc[i][j][r];
                if (BIAS) x += bv;
                if (PRELU) x = (x >= 0.f) ? x : alpha * x;
                if (RES) x += Rb[(long)row * ldr + col];
                Ob[(long)row * ldo + col] = x;
            }
        }
}

// ---------------------------------------------------------------------------
extern "C" void kernel_launch(void* const* d_in, const int* in_sizes, int n_in,
                              void* d_out, int out_size, void* d_ws, size_t ws_size,
                              hipStream_t stream)
{
    (void)in_sizes; (void)n_in; (void)out_size;
    const float* src    = (const float*)d_in[0];
    const float* ssrc   = (const float*)d_in[1];
    const float* Wq_t   = (const float*)d_in[2];
    const float* Wk_t   = (const float*)d_in[3];
    const float* Wv_t   = (const float*)d_in[4];
    const float* Wo_t   = (const float*)d_in[5];
    const float* Wq_s   = (const float*)d_in[6];
    const float* Wk_s   = (const float*)d_in[7];
    const float* W1     = (const float*)d_in[8];
    const float* b1     = (const float*)d_in[9];
    const float* W2     = (const float*)d_in[10];
    const float* b2     = (const float*)d_in[11];
    const float* tsW1   = (const float*)d_in[12];
    const float* tsb1   = (const float*)d_in[13];
    const float* tsW2   = (const float*)d_in[14];
    const float* tsb2   = (const float*)d_in[15];
    const float* alphap = (const float*)d_in[16];
    const float* g1     = (const float*)d_in[17];
    const float* be1    = (const float*)d_in[18];
    const float* g2     = (const float*)d_in[19];
    const float* be2    = (const float*)d_in[20];
    const float* tsg1   = (const float*)d_in[21];
    const float* tsbe1  = (const float*)d_in[22];
    const float* tsg2   = (const float*)d_in[23];
    const float* tsbe2  = (const float*)d_in[24];
    const float* sg     = (const float*)d_in[25];
    const float* sbe    = (const float*)d_in[26];

    const long U = NBT_;
    float* ws     = (float*)d_ws;
    float* src2   = ws;               // f32 residual stream
    float* src3   = ws + U;
    float* mixout = ws + 2 * U;
    float* out_ts = (float*)d_out;
    float* out_sw = (float*)d_out + U;

    _Float16* hb    = (_Float16*)(ws + 3 * U);   // U-halves units
    _Float16* xbufH = hb;
    _Float16* attnH = hb + 1 * U;
    _Float16* hbufH = hb + 2 * U;
    _Float16* qkvh  = hb + 3 * U;     // [B*T, 1536] fused q|k|v (3U)
    _Float16* qksh  = hb + 6 * U;     // [B*C, 1024] fused qs|ks (2U)
    _Float16* swH   = hb + 8 * U;
    _Float16* wb    = hb + 9 * U;     // weights f16: 5.77M halves < 2U

    const int NS = 262144, NB = 1048576;
    _Float16* QKVW = wb;              // Wq|Wk|Wv rows 0..1535
    _Float16* WoH  = wb + 3 * NS;
    _Float16* QKsW = wb + 4 * NS;     // Wq_s|Wk_s rows 0..1023
    _Float16* W1H  = wb + 6 * NS;
    _Float16* W2H  = W1H + NB;
    _Float16* tW1H = W1H + 2 * NB;
    _Float16* tW2H = W1H + 3 * NB;

    // spatial score buffer tiers (f16, U halves per head slice)
    const size_t uaF = ws_size / ((size_t)U * 4);
    int G; _Float16* sbuf;
    if      (uaF >= 13) { G = 8; sbuf = hb + 11 * U; }
    else if (uaF >= 11) { G = 4; sbuf = hb + 11 * U; }
    else if (uaF >= 10) { G = 2; sbuf = hb + 11 * U; }
    else                { G = 2; sbuf = qkvh; }   // qkv dead during spatial

    // ---- convert weights to f16 ----
    WList wl;
    wl.s[0]=Wq_t; wl.s[1]=Wk_t; wl.s[2]=Wv_t; wl.s[3]=Wo_t; wl.s[4]=Wq_s; wl.s[5]=Wk_s;
    wl.s[6]=W1;   wl.s[7]=W2;   wl.s[8]=tsW1; wl.s[9]=tsW2;
    wl.h[0]=QKVW;        wl.h[1]=QKVW+NS;  wl.h[2]=QKVW+2*NS; wl.h[3]=WoH;
    wl.h[4]=QKsW;        wl.h[5]=QKsW+NS;  wl.h[6]=W1H;       wl.h[7]=W2H;
    wl.h[8]=tW1H;        wl.h[9]=tW2H;
    for (int i = 0; i < 6; i++) wl.n[i] = NS;
    for (int i = 6; i < 10; i++) wl.n[i] = NB;
    wconv<<<dim3(512, 1, 10), 256, 0, stream>>>(wl);

    const long sTC  = (long)T_ * C_;
    const long sCC  = (long)C_ * C_;
    const long sBCC = (long)B_ * sCC;
    const float* nfp = nullptr; _Float16* nhp = nullptr; float* nwp = nullptr;

    // ---- temporal attention ----
    ln512s<<<dim3(B_ * T_), 64, 0, stream>>>(src, g1, be1, xbufH);
    gemm3<false,false,false,1><<<dim3(64,24,1),256,0,stream>>>(
        xbufH,0,0,C_,  QKVW,0,0,C_,  nwp,qkvh,0,0,1536,
        nfp,0,0,0, nfp,nfp, C_, 1);

    flash_attn3<<<dim3(B_ * H_, T_ / 64), 256, 0, stream>>>(
        qkvh, qkvh + 512, qkvh + 1024, attnH, 1536);

    gemm3<false,false,true,0><<<dim3(64,8,1),256,0,stream>>>(
        attnH,0,0,C_,  WoH,0,0,C_,  src2,nhp,0,0,C_,
        src,0,0,C_, nfp,nfp, C_, 1);

    // ---- FFN block 1 ----
    ln512s<<<dim3(B_ * T_), 64, 0, stream>>>(src2, g2, be2, xbufH);
    for (int j = 0; j < 4; j++) {
        gemm3<true,true,false,1><<<dim3(64,8,1),256,0,stream>>>(
            xbufH,0,0,C_,  W1H + (long)j*512*C_,0,0,C_,  nwp,hbufH,0,0,512,
            nfp,0,0,0,  b1 + j*512, alphap, C_, 1);
        if (j == 0)
            gemm3<true,false,true,0><<<dim3(64,8,1),256,0,stream>>>(
                hbufH,0,0,512,  W2H + j*512,0,0,HID_,  src3,nhp,0,0,C_,
                src2,0,0,C_,  b2, nfp, 512, 1);
        else
            gemm3<false,false,true,0><<<dim3(64,8,1),256,0,stream>>>(
                hbufH,0,0,512,  W2H + j*512,0,0,HID_,  src3,nhp,0,0,C_,
                src3,0,0,C_,  nfp, nfp, 512, 1);
    }

    // ---- spatial attention (weights only, mean over heads) ----
    ln512s<<<dim3(B_ * C_), 64, 0, stream>>>(ssrc, sg, sbe, xbufH);
    gemm3<false,false,false,1><<<dim3(64,16,1),256,0,stream>>>(
        xbufH,0,0,L_,  QKsW,0,0,L_,  nwp,qksh,0,0,1024,
        nfp,0,0,0, nfp,nfp, L_, 1);
    for (int g0 = 0; g0 < H_; g0 += G) {
        gemm3<false,false,false,1><<<dim3(4,8,G*B_),256,0,stream>>>(
            qksh + g0*64,       64, (long)C_*1024, 1024,
            qksh + 512 + g0*64, 64, (long)C_*1024, 1024,
            nwp, sbuf, sBCC, sCC, C_,
            nfp,0,0,0, nfp,nfp, 64, B_);
        const bool first = (g0 == 0), last = (g0 + G == H_);
        if (first && last)
            softmax_accum512h<true,true ><<<dim3(B_ * C_), 64, 0, stream>>>(sbuf, out_sw, swH, G);
        else if (first)
            softmax_accum512h<true,false><<<dim3(B_ * C_), 64, 0, stream>>>(sbuf, out_sw, swH, G);
        else if (last)
            softmax_accum512h<false,true><<<dim3(B_ * C_), 64, 0, stream>>>(sbuf, out_sw, swH, G);
        else
            softmax_accum512h<false,false><<<dim3(B_ * C_), 64, 0, stream>>>(sbuf, out_sw, swH, G);
    }

    // ---- temporal-spatial mixing ----
    ln512s<<<dim3(B_ * T_), 64, 0, stream>>>(src3, tsg1, tsbe1, xbufH);
    gemm3<false,false,true,0><<<dim3(4,8,16),256,0,stream>>>(
        xbufH, 0, sTC, C_,
        swH,   0, sCC, C_,
        mixout,nhp, 0, sTC, C_,
        src3,  0, sTC, C_,
        nfp, nfp, C_, 16);

    // ---- FFN block 2 (into d_out) ----
    ln512s<<<dim3(B_ * T_), 64, 0, stream>>>(mixout, tsg2, tsbe2, xbufH);
    for (int j = 0; j < 4; j++) {
        gemm3<true,true,false,1><<<dim3(64,8,1),256,0,stream>>>(
            xbufH,0,0,C_,  tW1H + (long)j*512*C_,0,0,C_,  nwp,hbufH,0,0,512,
            nfp,0,0,0,  tsb1 + j*512, alphap, C_, 1);
        if (j == 0)
            gemm3<true,false,true,0><<<dim3(64,8,1),256,0,stream>>>(
                hbufH,0,0,512,  tW2H + j*512,0,0,HID_,  out_ts,nhp,0,0,C_,
                mixout,0,0,C_,  tsb2, nfp, 512, 1);
        else
            gemm3<false,false,true,0><<<dim3(64,8,1),256,0,stream>>>(
                hbufH,0,0,512,  tW2H + j*512,0,0,HID_,  out_ts,nhp,0,0,C_,
                out_ts,0,0,C_,  nfp, nfp, 512, 1);
    }
}